// Round 2
// baseline (18580.923 us; speedup 1.0000x reference)
//
#include <hip/hip_runtime.h>

#define LSEQ 512
#define BATCH 256
#define KDIM 256
#define STATE 128

using f32x4  = __attribute__((ext_vector_type(4))) float;
using short8 = __attribute__((ext_vector_type(8))) short;

__device__ __forceinline__ float bf2f(unsigned short u){
  return __uint_as_float(((unsigned int)u) << 16);
}
__device__ __forceinline__ unsigned short f2bf(float f){
  unsigned int u = __float_as_uint(f);
  u += 0x7FFFu + ((u >> 16) & 1u);   // RNE
  return (unsigned short)(u >> 16);
}
__device__ __forceinline__ float fast_tanh(float x){
  float ax = fabsf(x);
  float e  = __expf(2.0f * ax);          // >= 1, inf-safe
  float t  = 1.0f - 2.0f / (e + 1.0f);
  return copysignf(t, x);
}
__device__ __forceinline__ float fast_sig(float x){
  return 1.0f / (1.0f + __expf(-x));
}
__device__ __forceinline__ f32x4 mfma16(short8 a, short8 b, f32x4 c){
  return __builtin_amdgcn_mfma_f32_16x16x32_bf16(a, b, c, 0, 0, 0);
}

// XOR swizzles (row-stride-specific); XOR bits 4..6 of byte addr, keeps 16B alignment
__device__ __forceinline__ int swz128 (int b){ return b ^ ((((b >> 7) & 7) << 4)); }
__device__ __forceinline__ int swz256 (int b){ return b ^ ((((b >> 8) & 7) << 4)); }
__device__ __forceinline__ int swz512 (int b){ return b ^ ((((b >> 9) & 7) << 4)); }
__device__ __forceinline__ int swz1024(int b){ return b ^ ((((b >>10) & 7) << 4)); }

// ---------------- weight convert: f32 [K,N] (row off) -> bf16 transposed [N][K] ----------------
struct WDesc { const float* src; unsigned short* dst; int K, N, ld, rowoff; };
struct WDescs { WDesc d[17]; };

__global__ __launch_bounds__(256,4) void convert_weights(WDescs ds){
  WDesc w = ds.d[blockIdx.y];
  int total = w.K * w.N;
  int idx = blockIdx.x * 256 + threadIdx.x;
  if (idx < total){
    int n = idx / w.K;
    int k = idx - n * w.K;
    w.dst[idx] = f2bf(w.src[(size_t)(w.rowoff + k) * w.ld + n]);
  }
}

// ---------------- multi-descriptor bf16 MFMA GEMM ----------------
// C[R,N] = act(A[R,K] @ Bt^T + bias); blockIdx.z picks the descriptor.
// A: bf16 (or f32 if a_f32) row-major, lda.  Bt: bf16 [N][K].  C: bf16, ldc, col offset coff.
struct GArg {
  const void* A; const unsigned short* Bt; const float* bias;
  unsigned short* C; int lda, ldc, coff, K, act, a_f32;
};
struct GArgs { GArg g[4]; };

__global__ __launch_bounds__(256,2) void gemm_multi(GArgs args){
  GArg ga = args.g[blockIdx.z];
  __shared__ __align__(16) unsigned short lsA[128*64];
  __shared__ __align__(16) unsigned short lsB[128*64];
  const int tid  = threadIdx.x;
  const int wave = tid >> 6, lane = tid & 63;
  const int col_l = lane & 15, rgrp = lane >> 4;
  const int m0 = blockIdx.x * 128, n0 = blockIdx.y * 128;
  const int wm = (wave >> 1) * 64, wn = (wave & 1) * 64;

  f32x4 acc[4][4];
  const f32x4 z4 = {0.f,0.f,0.f,0.f};
  #pragma unroll
  for (int i=0;i<4;i++){ acc[i][0]=z4; acc[i][1]=z4; acc[i][2]=z4; acc[i][3]=z4; }

  const int srow = tid >> 1;
  const int sbe  = (tid & 1) * 32;    // element offset within the 64-wide k-tile

  for (int k0 = 0; k0 < ga.K; k0 += 64){
    uint4 av[4], bv[4];
    if (ga.a_f32){
      const float* Ap = (const float*)ga.A + (size_t)(m0 + srow) * ga.lda + k0 + sbe;
      uint4 fv[8];
      #pragma unroll
      for (int i=0;i<8;i++) fv[i] = *(const uint4*)((const char*)Ap + i*16);
      #pragma unroll
      for (int i=0;i<4;i++){
        const float* f = (const float*)&fv[i*2];
        uint4 o;
        o.x = (unsigned)f2bf(f[0]) | ((unsigned)f2bf(f[1]) << 16);
        o.y = (unsigned)f2bf(f[2]) | ((unsigned)f2bf(f[3]) << 16);
        o.z = (unsigned)f2bf(f[4]) | ((unsigned)f2bf(f[5]) << 16);
        o.w = (unsigned)f2bf(f[6]) | ((unsigned)f2bf(f[7]) << 16);
        av[i] = o;
      }
    } else {
      const unsigned short* Ap = (const unsigned short*)ga.A + (size_t)(m0 + srow) * ga.lda + k0 + sbe;
      #pragma unroll
      for (int i=0;i<4;i++) av[i] = *(const uint4*)((const char*)Ap + i*16);
    }
    const unsigned short* Bp = ga.Bt + (size_t)(n0 + srow) * ga.K + k0 + sbe;
    #pragma unroll
    for (int i=0;i<4;i++) bv[i] = *(const uint4*)((const char*)Bp + i*16);

    __syncthreads();   // previous iter's frag reads complete
    #pragma unroll
    for (int i=0;i<4;i++){
      *(uint4*)((char*)lsA + swz128(srow*128 + sbe*2 + i*16)) = av[i];
      *(uint4*)((char*)lsB + swz128(srow*128 + sbe*2 + i*16)) = bv[i];
    }
    __syncthreads();
    #pragma unroll
    for (int kk=0; kk<2; kk++){
      short8 af[4], bfr[4];
      #pragma unroll
      for (int mt=0; mt<4; mt++)
        af[mt] = *(const short8*)((const char*)lsA + swz128((wm + mt*16 + col_l)*128 + kk*64 + rgrp*16));
      #pragma unroll
      for (int nt=0; nt<4; nt++)
        bfr[nt] = *(const short8*)((const char*)lsB + swz128((wn + nt*16 + col_l)*128 + kk*64 + rgrp*16));
      #pragma unroll
      for (int mt=0; mt<4; mt++)
        #pragma unroll
        for (int nt=0; nt<4; nt++)
          acc[mt][nt] = mfma16(af[mt], bfr[nt], acc[mt][nt]);
    }
  }
  #pragma unroll
  for (int nt=0; nt<4; nt++){
    int col = n0 + wn + nt*16 + col_l;
    float bb = ga.bias ? ga.bias[col] : 0.0f;
    #pragma unroll
    for (int mt=0; mt<4; mt++){
      #pragma unroll
      for (int r=0; r<4; r++){
        int row = m0 + wm + mt*16 + rgrp*4 + r;
        float v = acc[mt][nt][r] + bb;
        if (ga.act == 1) v = fast_tanh(v);
        ga.C[(size_t)row * ga.ldc + ga.coff + col] = f2bf(v);
      }
    }
  }
}

// ---------------- phase B: tanh-RNN chunk, W_hh held in VGPRs ----------------
__global__ __launch_bounds__(256,1) void rnn_chunk(
    const unsigned short* __restrict__ rnn_in,   // [nsteps*B,256] bf16 (chunk base)
    const unsigned short* __restrict__ Whh_t,    // [256 n][256 k] bf16
    const float* __restrict__ b_hh,
    unsigned short* __restrict__ cat_d,          // chunk cat buffer, cols [0,256), ld 512
    float* __restrict__ dn_out,                  // [B,256] f32 (written at global last step)
    unsigned short* __restrict__ d_state,        // [B,256] bf16 persistent
    int t0, int nsteps)
{
  __shared__ __align__(16) unsigned short dls[16*256];   // d, row stride 512B, swizzled
  const int tid = threadIdx.x, wave = tid >> 6, lane = tid & 63;
  const int col_l = lane & 15, rgrp = lane >> 4;
  const int brow0 = blockIdx.x * 16;
  const int ncol = wave * 64;

  short8 bfr[4][8];
  #pragma unroll
  for (int nt=0; nt<4; nt++){
    const unsigned short* bp = Whh_t + (size_t)(ncol + nt*16 + col_l) * 256;
    #pragma unroll
    for (int kk=0; kk<8; kk++)
      bfr[nt][kk] = *(const short8*)(bp + kk*32 + rgrp*8);
  }
  float bias[4];
  #pragma unroll
  for (int nt=0; nt<4; nt++) bias[nt] = b_hh[ncol + nt*16 + col_l];

  if (t0 == 0){
    for (int i = tid; i < 16*256; i += 256){
      int row = i >> 8, col = i & 255;
      *(unsigned short*)((char*)dls + swz512(row*512 + col*2)) = 0;
    }
  } else {
    const unsigned short* ds = d_state + (size_t)brow0 * 256;
    for (int i = tid; i < 16*256; i += 256){
      int row = i >> 8, col = i & 255;
      *(unsigned short*)((char*)dls + swz512(row*512 + col*2)) = ds[row*256 + col];
    }
  }
  __syncthreads();

  for (int tl=0; tl<nsteps; tl++){
    unsigned short rv[4][4];
    const unsigned short* rp = rnn_in + (size_t)(tl*BATCH + brow0) * 256;
    #pragma unroll
    for (int nt=0; nt<4; nt++)
      #pragma unroll
      for (int r=0; r<4; r++)
        rv[nt][r] = rp[(size_t)(rgrp*4 + r)*256 + ncol + nt*16 + col_l];

    f32x4 acc[4];
    const f32x4 z4 = {0.f,0.f,0.f,0.f};
    acc[0]=z4; acc[1]=z4; acc[2]=z4; acc[3]=z4;
    #pragma unroll
    for (int kk=0; kk<8; kk++){
      short8 af = *(const short8*)((const char*)dls + swz512((lane & 15)*512 + kk*64 + rgrp*16));
      #pragma unroll
      for (int nt=0; nt<4; nt++)
        acc[nt] = mfma16(af, bfr[nt][kk], acc[nt]);
    }
    __syncthreads();   // all waves done reading d
    #pragma unroll
    for (int nt=0; nt<4; nt++){
      #pragma unroll
      for (int r=0; r<4; r++){
        float h = acc[nt][r] + bf2f(rv[nt][r]) + bias[nt];
        float d = fast_tanh(h);
        int row = rgrp*4 + r, col = ncol + nt*16 + col_l;
        unsigned short db = f2bf(d);
        *(unsigned short*)((char*)dls + swz512(row*512 + col*2)) = db;
        cat_d[(size_t)(tl*BATCH + brow0 + row)*512 + col] = db;
        if (t0 + tl == LSEQ-1) dn_out[(size_t)(brow0 + row)*256 + col] = d;
      }
    }
    __syncthreads();
  }
  // persist d state
  unsigned short* dso = d_state + (size_t)brow0 * 256;
  for (int i = tid; i < 16*256; i += 256){
    int row = i >> 8, col = i & 255;
    dso[row*256 + col] = *(const unsigned short*)((const char*)dls + swz512(row*512 + col*2));
  }
}

// ---------------- phase D: z recurrence chunk (DBlocks), weights streamed from L2 ----------------
__global__ __launch_bounds__(512,2) void zrec_chunk(
    const unsigned short* __restrict__ pre1p, const unsigned short* __restrict__ pre2p,
    const unsigned short* __restrict__ pre1q, const unsigned short* __restrict__ pre2q, // chunk [ns*B,512]
    const unsigned short* __restrict__ Wz,   // 4 x [512 n][128 k] bf16: f1z_p,f2z_p,f1z_q,f2z_q
    const unsigned short* __restrict__ Wh,   // 3 x [128 n][512 k] bf16: mu_p, ls_p, mu_q
    const float* __restrict__ mu_b_p, const float* __restrict__ ls_b_p, const float* __restrict__ mu_b_q,
    const float* __restrict__ eps,           // global [L*B,128] f32
    float* __restrict__ out_mu, float* __restrict__ out_ls, float* __restrict__ out_zn,
    unsigned short* __restrict__ z_state,    // [B,128] bf16 persistent
    int t0, int nsteps)
{
  __shared__ __align__(16) unsigned short zls[16*128];   // z, row stride 256B, swizzled
  __shared__ __align__(16) unsigned short tp [16*512];   // t_post, row stride 1024B
  __shared__ __align__(16) unsigned short tq [16*512];   // t_prior
  const int tid = threadIdx.x, wave = tid >> 6, lane = tid & 63;
  const int col_l = lane & 15, rgrp = lane >> 4;
  const int brow0 = blockIdx.x * 16;
  const int ncol = wave * 64;            // GEMM1 n-slice
  const int hcol = wave * 16 + col_l;    // GEMM2 column (N=128)

  const float hb0 = mu_b_p[hcol], hb1 = ls_b_p[hcol], hb2 = mu_b_q[hcol];
  const unsigned short* pres[4] = {pre1p, pre2p, pre1q, pre2q};

  if (t0 == 0){
    for (int i = tid; i < 16*128; i += 512){
      int row = i >> 7, col = i & 127;
      *(unsigned short*)((char*)zls + swz256(row*256 + col*2)) = 0;
    }
  } else {
    const unsigned short* zs = z_state + (size_t)brow0 * 128;
    for (int i = tid; i < 16*128; i += 512){
      int row = i >> 7, col = i & 127;
      *(unsigned short*)((char*)zls + swz256(row*256 + col*2)) = zs[row*128 + col];
    }
  }
  __syncthreads();

  for (int tl=0; tl<nsteps; tl++){
    const int t = t0 + tl;
    short8 af[4];
    #pragma unroll
    for (int kk=0; kk<4; kk++)
      af[kk] = *(const short8*)((const char*)zls + swz256((lane & 15)*256 + kk*64 + rgrp*16));

    float tv[2][16];
    #pragma unroll
    for (int g=0; g<2; g++){          // 0 = posterior, 1 = prior
      float h[2][16];
      #pragma unroll
      for (int f=0; f<2; f++){        // 0 = f1 (tanh), 1 = f2 (sigmoid)
        const unsigned short* W = Wz + (size_t)(g*2 + f) * 65536;
        f32x4 acc[4];
        const f32x4 z4 = {0.f,0.f,0.f,0.f};
        acc[0]=z4; acc[1]=z4; acc[2]=z4; acc[3]=z4;
        #pragma unroll
        for (int nt=0; nt<4; nt++){
          const unsigned short* wp = W + (size_t)(ncol + nt*16 + col_l) * 128;
          #pragma unroll
          for (int kk=0; kk<4; kk++){
            short8 bfr = *(const short8*)(wp + kk*32 + rgrp*8);
            acc[nt] = mfma16(af[kk], bfr, acc[nt]);
          }
        }
        const unsigned short* prep = pres[g*2 + f] + (size_t)(tl*BATCH + brow0) * 512;
        #pragma unroll
        for (int nt=0; nt<4; nt++)
          #pragma unroll
          for (int r=0; r<4; r++)
            h[f][nt*4 + r] = acc[nt][r] + bf2f(prep[(size_t)(rgrp*4 + r)*512 + ncol + nt*16 + col_l]);
      }
      #pragma unroll
      for (int i=0; i<16; i++) tv[g][i] = fast_tanh(h[0][i]) * fast_sig(h[1][i]);
    }
    #pragma unroll
    for (int nt=0; nt<4; nt++){
      #pragma unroll
      for (int r=0; r<4; r++){
        int row = rgrp*4 + r, col = ncol + nt*16 + col_l;
        *(unsigned short*)((char*)tp + swz1024(row*1024 + col*2)) = f2bf(tv[0][nt*4 + r]);
        *(unsigned short*)((char*)tq + swz1024(row*1024 + col*2)) = f2bf(tv[1][nt*4 + r]);
      }
    }
    __syncthreads();
    f32x4 hacc[3];
    const f32x4 z4 = {0.f,0.f,0.f,0.f};
    hacc[0]=z4; hacc[1]=z4; hacc[2]=z4;
    const unsigned short* W0 = Wh + (size_t)hcol * 512;
    const unsigned short* W1 = Wh + 65536  + (size_t)hcol * 512;
    const unsigned short* W2 = Wh + 131072 + (size_t)hcol * 512;
    #pragma unroll
    for (int kk=0; kk<16; kk++){
      short8 ap = *(const short8*)((const char*)tp + swz1024((lane & 15)*1024 + kk*64 + rgrp*16));
      short8 aq = *(const short8*)((const char*)tq + swz1024((lane & 15)*1024 + kk*64 + rgrp*16));
      short8 b0 = *(const short8*)(W0 + kk*32 + rgrp*8);
      short8 b1 = *(const short8*)(W1 + kk*32 + rgrp*8);
      short8 b2 = *(const short8*)(W2 + kk*32 + rgrp*8);
      hacc[0] = mfma16(ap, b0, hacc[0]);
      hacc[1] = mfma16(ap, b1, hacc[1]);
      hacc[2] = mfma16(aq, b2, hacc[2]);
    }
    #pragma unroll
    for (int r=0; r<4; r++){
      int row = rgrp*4 + r;
      size_t grow = (size_t)t*BATCH + brow0 + row;
      float mu = (hacc[2][r] + hb2) + (hacc[0][r] + hb0);
      float ls = hacc[1][r] + hb1;
      float e  = eps[grow*STATE + hcol];
      float z  = mu + __expf(0.5f * ls) * e;
      out_mu[grow*STATE + hcol] = mu;
      out_ls[grow*STATE + hcol] = ls;
      *(unsigned short*)((char*)zls + swz256(row*256 + hcol*2)) = f2bf(z);
      if (t == LSEQ-1) out_zn[(size_t)(brow0 + row)*STATE + hcol] = z;
    }
    __syncthreads();
  }
  // persist z state
  unsigned short* zso = z_state + (size_t)brow0 * 128;
  for (int i = tid; i < 16*128; i += 512){
    int row = i >> 7, col = i & 127;
    zso[row*128 + col] = *(const unsigned short*)((const char*)zls + swz256(row*256 + col*2));
  }
}

// ---------------- host launcher ----------------
extern "C" void kernel_launch(void* const* d_in, const int* in_sizes, int n_in,
                              void* d_out, int out_size, void* d_ws, size_t ws_size,
                              hipStream_t stream)
{
  const float* ext = (const float*)d_in[0];
  const float* obs = (const float*)d_in[1];
  const float* eps = (const float*)d_in[2];
  const float* Wu  = (const float*)d_in[3];
  const float* bu  = (const float*)d_in[4];
  const float* Wx  = (const float*)d_in[5];
  const float* bx  = (const float*)d_in[6];
  const float* W_ih= (const float*)d_in[7];
  const float* b_ih= (const float*)d_in[8];
  const float* W_hh= (const float*)d_in[9];
  const float* b_hh= (const float*)d_in[10];
  const float* Wa1 = (const float*)d_in[11];
  const float* ba1 = (const float*)d_in[12];
  const float* Wa2 = (const float*)d_in[13];
  const float* ba2 = (const float*)d_in[14];
  const float* pf1W= (const float*)d_in[15]; const float* pf1b = (const float*)d_in[16];
  const float* pf2W= (const float*)d_in[17]; const float* pf2b = (const float*)d_in[18];
  const float* pmuW= (const float*)d_in[19]; const float* pmub = (const float*)d_in[20];
  const float* plsW= (const float*)d_in[21]; const float* plsb = (const float*)d_in[22];
  const float* qf1W= (const float*)d_in[23]; const float* qf1b = (const float*)d_in[24];
  const float* qf2W= (const float*)d_in[25]; const float* qf2b = (const float*)d_in[26];
  const float* qmuW= (const float*)d_in[27]; const float* qmub = (const float*)d_in[28];

  // ---- pick chunk count from ws_size ----
  int NC = 0;
  const int cands[7] = {1,2,4,8,16,32,64};
  size_t rows = 0;
  for (int ci=0; ci<7; ci++){
    size_t r = (size_t)(LSEQ/cands[ci])*BATCH;
    size_t elems = 1600000 + r*3072;  // weights+states+margin + chunk buffers
    if (elems * 2 <= ws_size){ NC = cands[ci]; rows = r; break; }
  }
  if (!NC) return;  // cannot run
  const int nsteps = LSEQ/NC;
  const int gx = (int)(rows/128);

  unsigned short* ws = (unsigned short*)d_ws;
  size_t off = 0;
  auto alloc = [&](size_t elems){
    unsigned short* p = ws + off;
    off += (elems + 127) & ~(size_t)127;
    return p;
  };

  unsigned short* Wu_t  = alloc(64*256);
  unsigned short* Wx_t  = alloc(64*256);
  unsigned short* Wih_t = alloc(256*256);
  unsigned short* Whh_t = alloc(256*256);
  unsigned short* Wa1_t = alloc(512*256);   // [256 n][512 k]
  unsigned short* Wa2_t = alloc(256*256);
  unsigned short* f1a_p = alloc(256*512);   // [512 n][256 k]
  unsigned short* f2a_p = alloc(256*512);
  unsigned short* f1a_q = alloc(256*512);
  unsigned short* f2a_q = alloc(256*512);
  unsigned short* Wz    = alloc(4*512*128); // 4 x [512 n][128 k]
  unsigned short* Wh    = alloc(3*128*512); // 3 x [128 n][512 k]
  unsigned short* d_state = alloc(256*256);
  unsigned short* z_state = alloc(256*128);
  unsigned short* bufA  = alloc(rows*256);  // u_emb / a1t
  unsigned short* bufB  = alloc(rows*256);  // rnnin / a_seq
  unsigned short* bufC  = alloc(rows*512);  // cat = [d | x]
  unsigned short* preP1 = alloc(rows*512);
  unsigned short* preP2 = alloc(rows*512);
  unsigned short* preQ1 = alloc(rows*512);
  unsigned short* preQ2 = alloc(rows*512);
  if (off * sizeof(unsigned short) > ws_size) return;

  float* out_mu = (float*)d_out;
  float* out_ls = out_mu + (size_t)LSEQ*BATCH*STATE;
  float* out_dn = out_ls + (size_t)LSEQ*BATCH*STATE;
  float* out_zn = out_dn + (size_t)BATCH*KDIM;

  WDescs wd;
  int wi = 0;
  auto add = [&](const float* s, unsigned short* d, int Kk, int Nn, int ld, int ro){
    wd.d[wi].src = s; wd.d[wi].dst = d; wd.d[wi].K = Kk; wd.d[wi].N = Nn;
    wd.d[wi].ld = ld; wd.d[wi].rowoff = ro; wi++;
  };
  add(Wu,   Wu_t,  64, 256, 256, 0);
  add(Wx,   Wx_t,  64, 256, 256, 0);
  add(W_ih, Wih_t, 256, 256, 256, 0);
  add(W_hh, Whh_t, 256, 256, 256, 0);
  add(Wa1,  Wa1_t, 512, 256, 256, 0);
  add(Wa2,  Wa2_t, 256, 256, 256, 0);
  add(pf1W, f1a_p, 256, 512, 512, 128);
  add(pf2W, f2a_p, 256, 512, 512, 128);
  add(qf1W, f1a_q, 256, 512, 512, 128);
  add(qf2W, f2a_q, 256, 512, 512, 128);
  add(pf1W, Wz + 0*65536, 128, 512, 512, 0);
  add(pf2W, Wz + 1*65536, 128, 512, 512, 0);
  add(qf1W, Wz + 2*65536, 128, 512, 512, 0);
  add(qf2W, Wz + 3*65536, 128, 512, 512, 0);
  add(pmuW, Wh + 0*65536, 512, 128, 128, 0);
  add(plsW, Wh + 1*65536, 512, 128, 128, 0);
  add(qmuW, Wh + 2*65536, 512, 128, 128, 0);

  convert_weights<<<dim3(512,17), 256, 0, stream>>>(wd);

  for (int c=0; c<NC; ++c){
    const int t0 = c * nsteps;
    const size_t row0 = (size_t)t0 * BATCH;

    GArgs e{};
    e.g[0] = GArg{ext + row0*64, Wu_t, bu, bufA, 64, 256, 0,   64, 1, 1};
    e.g[1] = GArg{obs + row0*64, Wx_t, bx, bufC, 64, 512, 256, 64, 1, 1};
    gemm_multi<<<dim3(gx,2,2), 256, 0, stream>>>(e);

    GArgs rn{};
    rn.g[0] = GArg{bufA, Wih_t, b_ih, bufB, 256, 256, 0, 256, 0, 0};
    gemm_multi<<<dim3(gx,2,1), 256, 0, stream>>>(rn);

    rnn_chunk<<<16, 256, 0, stream>>>(bufB, Whh_t, b_hh, bufC, out_dn, d_state, t0, nsteps);

    GArgs a1{};
    a1.g[0] = GArg{bufC, Wa1_t, ba1, bufA, 512, 256, 0, 512, 1, 0};
    gemm_multi<<<dim3(gx,2,1), 256, 0, stream>>>(a1);

    GArgs a2{};
    a2.g[0] = GArg{bufA, Wa2_t, ba2, bufB, 256, 256, 0, 256, 0, 0};
    gemm_multi<<<dim3(gx,2,1), 256, 0, stream>>>(a2);

    GArgs pr{};
    pr.g[0] = GArg{bufB, f1a_p, pf1b, preP1, 256, 512, 0, 256, 0, 0};
    pr.g[1] = GArg{bufB, f2a_p, pf2b, preP2, 256, 512, 0, 256, 0, 0};
    pr.g[2] = GArg{bufC, f1a_q, qf1b, preQ1, 512, 512, 0, 256, 0, 0};
    pr.g[3] = GArg{bufC, f2a_q, qf2b, preQ2, 512, 512, 0, 256, 0, 0};
    gemm_multi<<<dim3(gx,4,4), 256, 0, stream>>>(pr);

    zrec_chunk<<<16, 512, 0, stream>>>(preP1, preP2, preQ1, preQ2, Wz, Wh,
                                       pmub, plsb, qmub, eps, out_mu, out_ls, out_zn,
                                       z_state, t0, nsteps);
  }
}

// Round 3
// 12718.962 us; speedup vs baseline: 1.4609x; 1.4609x over previous
//
#include <hip/hip_runtime.h>

#define LSEQ 512
#define BATCH 256
#define KDIM 256
#define STATE 128

using f32x4  = __attribute__((ext_vector_type(4))) float;
using short8 = __attribute__((ext_vector_type(8))) short;

__device__ __forceinline__ float bf2f(unsigned short u){
  return __uint_as_float(((unsigned int)u) << 16);
}
__device__ __forceinline__ unsigned short f2bf(float f){
  unsigned int u = __float_as_uint(f);
  u += 0x7FFFu + ((u >> 16) & 1u);   // RNE
  return (unsigned short)(u >> 16);
}
__device__ __forceinline__ float fast_tanh(float x){
  float ax = fabsf(x);
  float e  = __expf(2.0f * ax);
  float t  = 1.0f - 2.0f / (e + 1.0f);
  return copysignf(t, x);
}
__device__ __forceinline__ float fast_sig(float x){
  return 1.0f / (1.0f + __expf(-x));
}
__device__ __forceinline__ f32x4 mfma16(short8 a, short8 b, f32x4 c){
  return __builtin_amdgcn_mfma_f32_16x16x32_bf16(a, b, c, 0, 0, 0);
}

__device__ __forceinline__ int swz128 (int b){ return b ^ ((((b >> 7) & 7) << 4)); }
__device__ __forceinline__ int swz256 (int b){ return b ^ ((((b >> 8) & 7) << 4)); }
__device__ __forceinline__ int swz512 (int b){ return b ^ ((((b >> 9) & 7) << 4)); }

// ---------------- weight convert: f32 src[rowoff+k][coloff+n] -> bf16 dst[n*K+k] ----------------
struct WDesc { const float* src; unsigned short* dst; int K, N, ld, rowoff, coloff; };
struct WDescs { WDesc d[24]; };

__global__ __launch_bounds__(256,4) void convert_weights(WDescs ds){
  WDesc w = ds.d[blockIdx.y];
  int total = w.K * w.N;
  int idx = blockIdx.x * 256 + threadIdx.x;
  if (idx < total){
    int n = idx / w.K;
    int k = idx - n * w.K;
    w.dst[idx] = f2bf(w.src[(size_t)(w.rowoff + k) * w.ld + w.coloff + n]);
  }
}

__global__ __launch_bounds__(256,1) void init_flags(int* flags){
  flags[blockIdx.x * 256 + threadIdx.x] = 0;
}

// ---------------- multi-descriptor bf16 MFMA GEMM ----------------
struct GArg {
  const void* A; const unsigned short* Bt; const float* bias;
  unsigned short* C; int lda, ldc, coff, K, act, a_f32;
};
struct GArgs { GArg g[4]; };

__global__ __launch_bounds__(256,2) void gemm_multi(GArgs args){
  GArg ga = args.g[blockIdx.z];
  __shared__ __align__(16) unsigned short lsA[128*64];
  __shared__ __align__(16) unsigned short lsB[128*64];
  const int tid  = threadIdx.x;
  const int wave = tid >> 6, lane = tid & 63;
  const int col_l = lane & 15, rgrp = lane >> 4;
  const int m0 = blockIdx.x * 128, n0 = blockIdx.y * 128;
  const int wm = (wave >> 1) * 64, wn = (wave & 1) * 64;

  f32x4 acc[4][4];
  const f32x4 z4 = {0.f,0.f,0.f,0.f};
  #pragma unroll
  for (int i=0;i<4;i++){ acc[i][0]=z4; acc[i][1]=z4; acc[i][2]=z4; acc[i][3]=z4; }

  const int srow = tid >> 1;
  const int sbe  = (tid & 1) * 32;

  for (int k0 = 0; k0 < ga.K; k0 += 64){
    uint4 av[4], bv[4];
    if (ga.a_f32){
      const float* Ap = (const float*)ga.A + (size_t)(m0 + srow) * ga.lda + k0 + sbe;
      uint4 fv[8];
      #pragma unroll
      for (int i=0;i<8;i++) fv[i] = *(const uint4*)((const char*)Ap + i*16);
      #pragma unroll
      for (int i=0;i<4;i++){
        const float* f = (const float*)&fv[i*2];
        uint4 o;
        o.x = (unsigned)f2bf(f[0]) | ((unsigned)f2bf(f[1]) << 16);
        o.y = (unsigned)f2bf(f[2]) | ((unsigned)f2bf(f[3]) << 16);
        o.z = (unsigned)f2bf(f[4]) | ((unsigned)f2bf(f[5]) << 16);
        o.w = (unsigned)f2bf(f[6]) | ((unsigned)f2bf(f[7]) << 16);
        av[i] = o;
      }
    } else {
      const unsigned short* Ap = (const unsigned short*)ga.A + (size_t)(m0 + srow) * ga.lda + k0 + sbe;
      #pragma unroll
      for (int i=0;i<4;i++) av[i] = *(const uint4*)((const char*)Ap + i*16);
    }
    const unsigned short* Bp = ga.Bt + (size_t)(n0 + srow) * ga.K + k0 + sbe;
    #pragma unroll
    for (int i=0;i<4;i++) bv[i] = *(const uint4*)((const char*)Bp + i*16);

    __syncthreads();
    #pragma unroll
    for (int i=0;i<4;i++){
      *(uint4*)((char*)lsA + swz128(srow*128 + sbe*2 + i*16)) = av[i];
      *(uint4*)((char*)lsB + swz128(srow*128 + sbe*2 + i*16)) = bv[i];
    }
    __syncthreads();
    #pragma unroll
    for (int kk=0; kk<2; kk++){
      short8 af[4], bfr[4];
      #pragma unroll
      for (int mt=0; mt<4; mt++)
        af[mt] = *(const short8*)((const char*)lsA + swz128((wm + mt*16 + col_l)*128 + kk*64 + rgrp*16));
      #pragma unroll
      for (int nt=0; nt<4; nt++)
        bfr[nt] = *(const short8*)((const char*)lsB + swz128((wn + nt*16 + col_l)*128 + kk*64 + rgrp*16));
      #pragma unroll
      for (int mt=0; mt<4; mt++)
        #pragma unroll
        for (int nt=0; nt<4; nt++)
          acc[mt][nt] = mfma16(af[mt], bfr[nt], acc[mt][nt]);
    }
  }
  #pragma unroll
  for (int nt=0; nt<4; nt++){
    int col = n0 + wn + nt*16 + col_l;
    float bb = ga.bias ? ga.bias[col] : 0.0f;
    #pragma unroll
    for (int mt=0; mt<4; mt++){
      #pragma unroll
      for (int r=0; r<4; r++){
        int row = m0 + wm + mt*16 + rgrp*4 + r;
        float v = acc[mt][nt][r] + bb;
        if (ga.act == 1) v = fast_tanh(v);
        ga.C[(size_t)row * ga.ldc + ga.coff + col] = f2bf(v);
      }
    }
  }
}

// ---------------- phase B: tanh-RNN chunk, W_hh held in VGPRs ----------------
__global__ __launch_bounds__(256,1) void rnn_chunk(
    const unsigned short* __restrict__ rnn_in,
    const unsigned short* __restrict__ Whh_t,
    const float* __restrict__ b_hh,
    unsigned short* __restrict__ cat_d,
    float* __restrict__ dn_out,
    unsigned short* __restrict__ d_state,
    int t0, int nsteps)
{
  __shared__ __align__(16) unsigned short dls[16*256];
  const int tid = threadIdx.x, wave = tid >> 6, lane = tid & 63;
  const int col_l = lane & 15, rgrp = lane >> 4;
  const int brow0 = blockIdx.x * 16;
  const int ncol = wave * 64;

  short8 bfr[4][8];
  #pragma unroll
  for (int nt=0; nt<4; nt++){
    const unsigned short* bp = Whh_t + (size_t)(ncol + nt*16 + col_l) * 256;
    #pragma unroll
    for (int kk=0; kk<8; kk++)
      bfr[nt][kk] = *(const short8*)(bp + kk*32 + rgrp*8);
  }
  float bias[4];
  #pragma unroll
  for (int nt=0; nt<4; nt++) bias[nt] = b_hh[ncol + nt*16 + col_l];

  if (t0 == 0){
    for (int i = tid; i < 16*256; i += 256){
      int row = i >> 8, col = i & 255;
      *(unsigned short*)((char*)dls + swz512(row*512 + col*2)) = 0;
    }
  } else {
    const unsigned short* ds = d_state + (size_t)brow0 * 256;
    for (int i = tid; i < 16*256; i += 256){
      int row = i >> 8, col = i & 255;
      *(unsigned short*)((char*)dls + swz512(row*512 + col*2)) = ds[row*256 + col];
    }
  }
  __syncthreads();

  for (int tl=0; tl<nsteps; tl++){
    unsigned short rv[4][4];
    const unsigned short* rp = rnn_in + (size_t)(tl*BATCH + brow0) * 256;
    #pragma unroll
    for (int nt=0; nt<4; nt++)
      #pragma unroll
      for (int r=0; r<4; r++)
        rv[nt][r] = rp[(size_t)(rgrp*4 + r)*256 + ncol + nt*16 + col_l];

    f32x4 acc[4];
    const f32x4 z4 = {0.f,0.f,0.f,0.f};
    acc[0]=z4; acc[1]=z4; acc[2]=z4; acc[3]=z4;
    #pragma unroll
    for (int kk=0; kk<8; kk++){
      short8 af = *(const short8*)((const char*)dls + swz512((lane & 15)*512 + kk*64 + rgrp*16));
      #pragma unroll
      for (int nt=0; nt<4; nt++)
        acc[nt] = mfma16(af, bfr[nt][kk], acc[nt]);
    }
    __syncthreads();
    #pragma unroll
    for (int nt=0; nt<4; nt++){
      #pragma unroll
      for (int r=0; r<4; r++){
        float h = acc[nt][r] + bf2f(rv[nt][r]) + bias[nt];
        float d = fast_tanh(h);
        int row = rgrp*4 + r, col = ncol + nt*16 + col_l;
        unsigned short db = f2bf(d);
        *(unsigned short*)((char*)dls + swz512(row*512 + col*2)) = db;
        cat_d[(size_t)(tl*BATCH + brow0 + row)*512 + col] = db;
        if (t0 + tl == LSEQ-1) dn_out[(size_t)(brow0 + row)*256 + col] = d;
      }
    }
    __syncthreads();
  }
  unsigned short* dso = d_state + (size_t)brow0 * 256;
  for (int i = tid; i < 16*256; i += 256){
    int row = i >> 8, col = i & 255;
    dso[row*256 + col] = *(const unsigned short*)((const char*)dls + swz512(row*512 + col*2));
  }
}

// ---------------- phase D: weight-stationary z recurrence across 4 CUs per group ----------------
// 16 groups x 16 batch rows x 4 roles; 512 threads (8 waves).
// role 0: posterior t-cols 0-255 + mu_p|ls_p k 0-255    role 1: posterior 256-511 + mu_p|ls_p k 256-511
// role 2: prior t-cols 0-255 + mu_q k 0-255             role 3: prior 256-511 + mu_q k 256-511
__global__ __launch_bounds__(512) void zrec_mb(
    const unsigned short* __restrict__ preP1, const unsigned short* __restrict__ preP2,
    const unsigned short* __restrict__ preQ1, const unsigned short* __restrict__ preQ2,
    const unsigned short* __restrict__ Wzz,  // [4 roles][2 mats][256 n][128 k]
    const unsigned short* __restrict__ W2,   // [4 roles][2 mats][128 n][256 k]
    const float* __restrict__ pmub, const float* __restrict__ plsb, const float* __restrict__ qmub,
    const float* __restrict__ eps,
    float* __restrict__ out_mu, float* __restrict__ out_ls, float* __restrict__ out_zn,
    unsigned short* __restrict__ z_state,
    float* __restrict__ mb, int* __restrict__ flags,
    int t0, int nsteps)
{
  __shared__ __align__(16) unsigned short zls[16*128];  // [16][128] stride 256B, swz256
  __shared__ __align__(16) unsigned short tls[16*256];  // [16][256] stride 512B, swz512
  const int tid = threadIdx.x, wave = tid >> 6, lane = tid & 63;
  const int col_l = lane & 15, rgrp = lane >> 4;
  const int bid = blockIdx.x;
  const int c   = (bid >> 3) & 3;                 // role
  const int g   = (bid & 7) + ((bid >> 5) << 3);  // group (XCD-local members)
  const int brow0 = g * 16;
  const int NT2 = (c < 2) ? 2 : 1;

  const unsigned short* pA = (c < 2) ? preP1 : preQ1;
  const unsigned short* pB = (c < 2) ? preP2 : preQ2;
  const int cb = (c & 1) * 256;

  // GEMM1 weights -> VGPRs (64 regs)
  short8 w1[2][2][4];
  {
    const unsigned short* wz = Wzz + (size_t)c * 65536;
    #pragma unroll
    for (int m=0; m<2; m++)
      #pragma unroll
      for (int nt=0; nt<2; nt++){
        int n = wave*32 + nt*16 + col_l;
        #pragma unroll
        for (int kk=0; kk<4; kk++)
          w1[m][nt][kk] = *(const short8*)(wz + (size_t)(m*256 + n)*128 + kk*32 + rgrp*8);
      }
  }
  // GEMM2 weights -> VGPRs (<=64 regs)
  short8 w2r[2][8];
  {
    const unsigned short* wp = W2 + (size_t)c * 65536;
    #pragma unroll
    for (int nt=0; nt<2; nt++){
      if (nt < NT2){
        int ccol = wave*(16*((c<2)?2:1)) + nt*16;
        int mat = (c < 2) ? (ccol >> 7) : 0;
        int n   = (ccol & 127) + col_l;
        #pragma unroll
        for (int kk=0; kk<8; kk++)
          w2r[nt][kk] = *(const short8*)(wp + (size_t)(mat*128 + n)*256 + kk*32 + rgrp*8);
      }
    }
  }
  const int zcol = wave*16 + col_l;   // this thread's z columns (rows rgrp*4+r)
  const float bp = pmub[zcol], bl = plsb[zcol], bq = qmub[zcol];
  int* const myflag = flags + (g*4 + c)*32;

  // init z
  if (t0 == 0){
    for (int i = tid; i < 16*128; i += 512){
      int row = i >> 7, col = i & 127;
      *(unsigned short*)((char*)zls + swz256(row*256 + col*2)) = 0;
    }
  } else {
    const unsigned short* zs = z_state + (size_t)brow0 * 128;
    for (int i = tid; i < 16*128; i += 512){
      int row = i >> 7, col = i & 127;
      *(unsigned short*)((char*)zls + swz256(row*256 + col*2)) = zs[row*128 + col];
    }
  }
  __syncthreads();

  auto LD_PRE = [&](int tl, unsigned short (&pa_)[2][4], unsigned short (&pb_)[2][4]){
    const unsigned short* bA = pA + ((size_t)tl*BATCH + brow0)*512 + cb;
    const unsigned short* bB = pB + ((size_t)tl*BATCH + brow0)*512 + cb;
    #pragma unroll
    for (int nt=0; nt<2; nt++)
      #pragma unroll
      for (int r=0; r<4; r++){
        int row = rgrp*4 + r, col = wave*32 + nt*16 + col_l;
        pa_[nt][r] = bA[(size_t)row*512 + col];
        pb_[nt][r] = bB[(size_t)row*512 + col];
      }
  };

  unsigned short pa0[2][4], pb0[2][4], pa1[2][4], pb1[2][4];
  LD_PRE(0, pa0, pb0);

  const f32x4 z4 = {0.f,0.f,0.f,0.f};
  for (int tl=0; tl<nsteps; ++tl){
    // eps for this step + pre for next step: issue early, consume late
    float er[4];
    #pragma unroll
    for (int r=0; r<4; r++){
      size_t grow = (size_t)(t0+tl)*BATCH + brow0 + rgrp*4 + r;
      er[r] = eps[grow*STATE + zcol];
    }
    int nx = (tl+1 < nsteps) ? tl+1 : tl;
    LD_PRE(nx, pa1, pb1);

    // GEMM1: z @ Wf (both mats), K=128
    short8 af1[4];
    #pragma unroll
    for (int kk=0; kk<4; kk++)
      af1[kk] = *(const short8*)((const char*)zls + swz256((lane & 15)*256 + kk*64 + rgrp*16));
    f32x4 a1[2][2];
    a1[0][0]=z4; a1[0][1]=z4; a1[1][0]=z4; a1[1][1]=z4;
    #pragma unroll
    for (int kk=0; kk<4; kk++)
      #pragma unroll
      for (int m=0; m<2; m++)
        #pragma unroll
        for (int nt=0; nt<2; nt++)
          a1[m][nt] = mfma16(af1[kk], w1[m][nt][kk], a1[m][nt]);

    #pragma unroll
    for (int nt=0; nt<2; nt++)
      #pragma unroll
      for (int r=0; r<4; r++){
        float h1 = a1[0][nt][r] + bf2f(pa0[nt][r]);
        float h2 = a1[1][nt][r] + bf2f(pb0[nt][r]);
        float tv = fast_tanh(h1) * fast_sig(h2);
        int row = rgrp*4 + r, tcol = wave*32 + nt*16 + col_l;
        *(unsigned short*)((char*)tls + swz512(row*512 + tcol*2)) = f2bf(tv);
      }
    __syncthreads();

    // GEMM2: t @ Wh (local k-slice), K=256
    f32x4 a2[2];
    a2[0]=z4; a2[1]=z4;
    #pragma unroll
    for (int kk=0; kk<8; kk++){
      short8 af2 = *(const short8*)((const char*)tls + swz512((lane & 15)*512 + kk*64 + rgrp*16));
      #pragma unroll
      for (int nt=0; nt<2; nt++)
        if (nt < NT2) a2[nt] = mfma16(af2, w2r[nt][kk], a2[nt]);
    }
    // publish partial
    float* slot = mb + ((size_t)(g*2 + (tl & 1))*4 + c)*4096;
    #pragma unroll
    for (int nt=0; nt<2; nt++)
      if (nt < NT2){
        #pragma unroll
        for (int r=0; r<4; r++){
          int ccol = wave*(16*((c<2)?2:1)) + nt*16 + col_l;
          slot[(rgrp*4 + r)*256 + ccol] = a2[nt][r];
        }
      }
    __syncthreads();   // all waves' stores vmcnt-drained
    if (lane == 0)
      __hip_atomic_fetch_add(myflag, 1, __ATOMIC_RELEASE, __HIP_MEMORY_SCOPE_AGENT);

    // wait peers
    const int target = 8*(tl+1);
    #pragma unroll
    for (int p=0; p<4; p++){
      if (p == c) continue;
      int* pf = flags + (g*4 + p)*32;
      while (__hip_atomic_load(pf, __ATOMIC_ACQUIRE, __HIP_MEMORY_SCOPE_AGENT) < target) {}
    }

    // reduce partials -> mu, ls, z (redundant on all roles; identical fp order)
    const float* mbb = mb + (size_t)(g*2 + (tl & 1))*4*4096;
    #pragma unroll
    for (int r=0; r<4; r++){
      int row = rgrp*4 + r;
      const float* r0 = mbb + row*256;
      float mup = r0[zcol]          + r0[4096 + zcol];
      float lsp = r0[128 + zcol]    + r0[4096 + 128 + zcol];
      float muq = r0[2*4096 + zcol] + r0[3*4096 + zcol];
      float mu  = (muq + bq) + (mup + bp);
      float ls  = lsp + bl;
      float z   = mu + __expf(0.5f * ls) * er[r];
      *(unsigned short*)((char*)zls + swz256(row*256 + zcol*2)) = f2bf(z);
      if (c == 0){
        size_t grow = (size_t)(t0+tl)*BATCH + brow0 + row;
        out_mu[grow*STATE + zcol] = mu;
        out_ls[grow*STATE + zcol] = ls;
        if (t0 + tl == LSEQ-1) out_zn[((size_t)(brow0 + row))*STATE + zcol] = z;
      }
    }
    __syncthreads();

    #pragma unroll
    for (int nt=0; nt<2; nt++)
      #pragma unroll
      for (int r=0; r<4; r++){ pa0[nt][r] = pa1[nt][r]; pb0[nt][r] = pb1[nt][r]; }
  }

  // persist z state (role 0 writes)
  if (c == 0){
    unsigned short* zso = z_state + (size_t)brow0 * 128;
    for (int i = tid; i < 16*128; i += 512){
      int row = i >> 7, col = i & 127;
      zso[row*128 + col] = *(const unsigned short*)((const char*)zls + swz256(row*256 + col*2));
    }
  }
}

// ---------------- host launcher ----------------
extern "C" void kernel_launch(void* const* d_in, const int* in_sizes, int n_in,
                              void* d_out, int out_size, void* d_ws, size_t ws_size,
                              hipStream_t stream)
{
  const float* ext = (const float*)d_in[0];
  const float* obs = (const float*)d_in[1];
  const float* eps = (const float*)d_in[2];
  const float* Wu  = (const float*)d_in[3];
  const float* bu  = (const float*)d_in[4];
  const float* Wx  = (const float*)d_in[5];
  const float* bx  = (const float*)d_in[6];
  const float* W_ih= (const float*)d_in[7];
  const float* b_ih= (const float*)d_in[8];
  const float* W_hh= (const float*)d_in[9];
  const float* b_hh= (const float*)d_in[10];
  const float* Wa1 = (const float*)d_in[11];
  const float* ba1 = (const float*)d_in[12];
  const float* Wa2 = (const float*)d_in[13];
  const float* ba2 = (const float*)d_in[14];
  const float* pf1W= (const float*)d_in[15]; const float* pf1b = (const float*)d_in[16];
  const float* pf2W= (const float*)d_in[17]; const float* pf2b = (const float*)d_in[18];
  const float* pmuW= (const float*)d_in[19]; const float* pmub = (const float*)d_in[20];
  const float* plsW= (const float*)d_in[21]; const float* plsb = (const float*)d_in[22];
  const float* qf1W= (const float*)d_in[23]; const float* qf1b = (const float*)d_in[24];
  const float* qf2W= (const float*)d_in[25]; const float* qf2b = (const float*)d_in[26];
  const float* qmuW= (const float*)d_in[27]; const float* qmub = (const float*)d_in[28];

  int NC = 0;
  const int cands[7] = {1,2,4,8,16,32,64};
  size_t rows = 0;
  for (int ci=0; ci<7; ci++){
    size_t r = (size_t)(LSEQ/cands[ci])*BATCH;
    size_t elems = 2700000 + r*3072;
    if (elems * 2 <= ws_size){ NC = cands[ci]; rows = r; break; }
  }
  if (!NC) return;
  const int nsteps = LSEQ/NC;
  const int gx = (int)(rows/128);

  unsigned short* ws = (unsigned short*)d_ws;
  size_t off = 0;
  auto alloc = [&](size_t elems){
    unsigned short* p = ws + off;
    off += (elems + 127) & ~(size_t)127;
    return p;
  };

  unsigned short* Wu_t  = alloc(64*256);
  unsigned short* Wx_t  = alloc(64*256);
  unsigned short* Wih_t = alloc(256*256);
  unsigned short* Whh_t = alloc(256*256);
  unsigned short* Wa1_t = alloc(512*256);
  unsigned short* Wa2_t = alloc(256*256);
  unsigned short* f1a_p = alloc(256*512);
  unsigned short* f2a_p = alloc(256*512);
  unsigned short* f1a_q = alloc(256*512);
  unsigned short* f2a_q = alloc(256*512);
  unsigned short* Wzz   = alloc(4*2*256*128);  // [role][mat][n][k]
  unsigned short* W2z   = alloc(4*2*128*256);  // [role][mat][n][k]
  unsigned short* d_state = alloc(256*256);
  unsigned short* z_state = alloc(256*128);
  float* mbx  = (float*)alloc(2*16*2*4*4096); // 16 groups x 2 parity x 4 roles x 4096 f32
  int*   flg  = (int*)alloc(2*2048);          // 16x4 flags, 32-int stride
  unsigned short* bufA  = alloc(rows*256);
  unsigned short* bufB  = alloc(rows*256);
  unsigned short* bufC  = alloc(rows*512);
  unsigned short* preP1 = alloc(rows*512);
  unsigned short* preP2 = alloc(rows*512);
  unsigned short* preQ1 = alloc(rows*512);
  unsigned short* preQ2 = alloc(rows*512);
  if (off * sizeof(unsigned short) > ws_size) return;

  float* out_mu = (float*)d_out;
  float* out_ls = out_mu + (size_t)LSEQ*BATCH*STATE;
  float* out_dn = out_ls + (size_t)LSEQ*BATCH*STATE;
  float* out_zn = out_dn + (size_t)BATCH*KDIM;

  WDescs wd;
  int wi = 0;
  auto add = [&](const float* s, unsigned short* d, int Kk, int Nn, int ld, int ro, int co){
    wd.d[wi].src = s; wd.d[wi].dst = d; wd.d[wi].K = Kk; wd.d[wi].N = Nn;
    wd.d[wi].ld = ld; wd.d[wi].rowoff = ro; wd.d[wi].coloff = co; wi++;
  };
  add(Wu,   Wu_t,  64, 256, 256, 0, 0);
  add(Wx,   Wx_t,  64, 256, 256, 0, 0);
  add(W_ih, Wih_t, 256, 256, 256, 0, 0);
  add(W_hh, Whh_t, 256, 256, 256, 0, 0);
  add(Wa1,  Wa1_t, 512, 256, 256, 0, 0);
  add(Wa2,  Wa2_t, 256, 256, 256, 0, 0);
  add(pf1W, f1a_p, 256, 512, 512, 128, 0);
  add(pf2W, f2a_p, 256, 512, 512, 128, 0);
  add(qf1W, f1a_q, 256, 512, 512, 128, 0);
  add(qf2W, f2a_q, 256, 512, 512, 128, 0);
  // Wzz: roles 0,1 posterior halves; 2,3 prior halves. mats f1,f2.
  for (int c=0; c<4; c++){
    const float* s1 = (c < 2) ? pf1W : qf1W;
    const float* s2 = (c < 2) ? pf2W : qf2W;
    add(s1, Wzz + (size_t)(c*2+0)*32768, 128, 256, 512, 0, (c&1)*256);
    add(s2, Wzz + (size_t)(c*2+1)*32768, 128, 256, 512, 0, (c&1)*256);
  }
  // W2: role 0/1: mu_p, ls_p k-halves; role 2/3: mu_q k-halves.
  add(pmuW, W2z + (size_t)(0*2+0)*32768, 256, 128, 128, 0,   0);
  add(plsW, W2z + (size_t)(0*2+1)*32768, 256, 128, 128, 0,   0);
  add(pmuW, W2z + (size_t)(1*2+0)*32768, 256, 128, 128, 256, 0);
  add(plsW, W2z + (size_t)(1*2+1)*32768, 256, 128, 128, 256, 0);
  add(qmuW, W2z + (size_t)(2*2+0)*32768, 256, 128, 128, 0,   0);
  add(qmuW, W2z + (size_t)(3*2+0)*32768, 256, 128, 128, 256, 0);

  convert_weights<<<dim3(512,24), 256, 0, stream>>>(wd);

  for (int c=0; c<NC; ++c){
    const int t0 = c * nsteps;
    const size_t row0 = (size_t)t0 * BATCH;

    GArgs e{};
    e.g[0] = GArg{ext + row0*64, Wu_t, bu, bufA, 64, 256, 0,   64, 1, 1};
    e.g[1] = GArg{obs + row0*64, Wx_t, bx, bufC, 64, 512, 256, 64, 1, 1};
    gemm_multi<<<dim3(gx,2,2), 256, 0, stream>>>(e);

    GArgs rn{};
    rn.g[0] = GArg{bufA, Wih_t, b_ih, bufB, 256, 256, 0, 256, 0, 0};
    gemm_multi<<<dim3(gx,2,1), 256, 0, stream>>>(rn);

    rnn_chunk<<<16, 256, 0, stream>>>(bufB, Whh_t, b_hh, bufC, out_dn, d_state, t0, nsteps);

    GArgs a1{};
    a1.g[0] = GArg{bufC, Wa1_t, ba1, bufA, 512, 256, 0, 512, 1, 0};
    gemm_multi<<<dim3(gx,2,1), 256, 0, stream>>>(a1);

    GArgs a2{};
    a2.g[0] = GArg{bufA, Wa2_t, ba2, bufB, 256, 256, 0, 256, 0, 0};
    gemm_multi<<<dim3(gx,2,1), 256, 0, stream>>>(a2);

    GArgs pr{};
    pr.g[0] = GArg{bufB, f1a_p, pf1b, preP1, 256, 512, 0, 256, 0, 0};
    pr.g[1] = GArg{bufB, f2a_p, pf2b, preP2, 256, 512, 0, 256, 0, 0};
    pr.g[2] = GArg{bufC, f1a_q, qf1b, preQ1, 512, 512, 0, 256, 0, 0};
    pr.g[3] = GArg{bufC, f2a_q, qf2b, preQ2, 512, 512, 0, 256, 0, 0};
    gemm_multi<<<dim3(gx,4,4), 256, 0, stream>>>(pr);

    init_flags<<<8, 256, 0, stream>>>(flg);
    zrec_mb<<<64, 512, 0, stream>>>(preP1, preP2, preQ1, preQ2, Wzz, W2z,
                                    pmub, plsb, qmub, eps, out_mu, out_ls, out_zn,
                                    z_state, mbx, flg, t0, nsteps);
  }
}

// Round 4
// 3979.336 us; speedup vs baseline: 4.6694x; 3.1963x over previous
//
#include <hip/hip_runtime.h>

#define LSEQ 512
#define BATCH 256
#define KDIM 256
#define STATE 128

using f32x4  = __attribute__((ext_vector_type(4))) float;
using short8 = __attribute__((ext_vector_type(8))) short;

__device__ __forceinline__ float bf2f(unsigned short u){
  return __uint_as_float(((unsigned int)u) << 16);
}
__device__ __forceinline__ unsigned short f2bf(float f){
  unsigned int u = __float_as_uint(f);
  u += 0x7FFFu + ((u >> 16) & 1u);   // RNE
  return (unsigned short)(u >> 16);
}
__device__ __forceinline__ float fast_tanh(float x){
  float ax = fabsf(x);
  float e  = __expf(2.0f * ax);
  float t  = 1.0f - 2.0f / (e + 1.0f);
  return copysignf(t, x);
}
__device__ __forceinline__ float fast_sig(float x){
  return 1.0f / (1.0f + __expf(-x));
}
__device__ __forceinline__ f32x4 mfma16(short8 a, short8 b, f32x4 c){
  return __builtin_amdgcn_mfma_f32_16x16x32_bf16(a, b, c, 0, 0, 0);
}

__device__ __forceinline__ int swz128 (int b){ return b ^ ((((b >> 7) & 7) << 4)); }
__device__ __forceinline__ int swz256 (int b){ return b ^ ((((b >> 8) & 7) << 4)); }
__device__ __forceinline__ int swz512 (int b){ return b ^ ((((b >> 9) & 7) << 4)); }

// relaxed agent-scope accessors: sc0|sc1 (bypass L1/L2 to coherent point), NO cache flush ops
__device__ __forceinline__ void mb_store(float* p, float v){
  __hip_atomic_store(p, v, __ATOMIC_RELAXED, __HIP_MEMORY_SCOPE_AGENT);
}
__device__ __forceinline__ float mb_load(const float* p){
  return __hip_atomic_load(p, __ATOMIC_RELAXED, __HIP_MEMORY_SCOPE_AGENT);
}

// ---------------- weight convert: f32 src[rowoff+k][coloff+n] -> bf16 dst[n*K+k] ----------------
struct WDesc { const float* src; unsigned short* dst; int K, N, ld, rowoff, coloff; };
struct WDescs { WDesc d[24]; };

__global__ __launch_bounds__(256,4) void convert_weights(WDescs ds){
  WDesc w = ds.d[blockIdx.y];
  int total = w.K * w.N;
  int idx = blockIdx.x * 256 + threadIdx.x;
  if (idx < total){
    int n = idx / w.K;
    int k = idx - n * w.K;
    w.dst[idx] = f2bf(w.src[(size_t)(w.rowoff + k) * w.ld + w.coloff + n]);
  }
}

__global__ __launch_bounds__(256,1) void init_flags(int* flags){
  flags[blockIdx.x * 256 + threadIdx.x] = 0;
}

// ---------------- multi-descriptor bf16 MFMA GEMM ----------------
struct GArg {
  const void* A; const unsigned short* Bt; const float* bias;
  unsigned short* C; int lda, ldc, coff, K, act, a_f32;
};
struct GArgs { GArg g[4]; };

__global__ __launch_bounds__(256,2) void gemm_multi(GArgs args){
  GArg ga = args.g[blockIdx.z];
  __shared__ __align__(16) unsigned short lsA[128*64];
  __shared__ __align__(16) unsigned short lsB[128*64];
  const int tid  = threadIdx.x;
  const int wave = tid >> 6, lane = tid & 63;
  const int col_l = lane & 15, rgrp = lane >> 4;
  const int m0 = blockIdx.x * 128, n0 = blockIdx.y * 128;
  const int wm = (wave >> 1) * 64, wn = (wave & 1) * 64;

  f32x4 acc[4][4];
  const f32x4 z4 = {0.f,0.f,0.f,0.f};
  #pragma unroll
  for (int i=0;i<4;i++){ acc[i][0]=z4; acc[i][1]=z4; acc[i][2]=z4; acc[i][3]=z4; }

  const int srow = tid >> 1;
  const int sbe  = (tid & 1) * 32;

  for (int k0 = 0; k0 < ga.K; k0 += 64){
    uint4 av[4], bv[4];
    if (ga.a_f32){
      const float* Ap = (const float*)ga.A + (size_t)(m0 + srow) * ga.lda + k0 + sbe;
      uint4 fv[8];
      #pragma unroll
      for (int i=0;i<8;i++) fv[i] = *(const uint4*)((const char*)Ap + i*16);
      #pragma unroll
      for (int i=0;i<4;i++){
        const float* f = (const float*)&fv[i*2];
        uint4 o;
        o.x = (unsigned)f2bf(f[0]) | ((unsigned)f2bf(f[1]) << 16);
        o.y = (unsigned)f2bf(f[2]) | ((unsigned)f2bf(f[3]) << 16);
        o.z = (unsigned)f2bf(f[4]) | ((unsigned)f2bf(f[5]) << 16);
        o.w = (unsigned)f2bf(f[6]) | ((unsigned)f2bf(f[7]) << 16);
        av[i] = o;
      }
    } else {
      const unsigned short* Ap = (const unsigned short*)ga.A + (size_t)(m0 + srow) * ga.lda + k0 + sbe;
      #pragma unroll
      for (int i=0;i<4;i++) av[i] = *(const uint4*)((const char*)Ap + i*16);
    }
    const unsigned short* Bp = ga.Bt + (size_t)(n0 + srow) * ga.K + k0 + sbe;
    #pragma unroll
    for (int i=0;i<4;i++) bv[i] = *(const uint4*)((const char*)Bp + i*16);

    __syncthreads();
    #pragma unroll
    for (int i=0;i<4;i++){
      *(uint4*)((char*)lsA + swz128(srow*128 + sbe*2 + i*16)) = av[i];
      *(uint4*)((char*)lsB + swz128(srow*128 + sbe*2 + i*16)) = bv[i];
    }
    __syncthreads();
    #pragma unroll
    for (int kk=0; kk<2; kk++){
      short8 af[4], bfr[4];
      #pragma unroll
      for (int mt=0; mt<4; mt++)
        af[mt] = *(const short8*)((const char*)lsA + swz128((wm + mt*16 + col_l)*128 + kk*64 + rgrp*16));
      #pragma unroll
      for (int nt=0; nt<4; nt++)
        bfr[nt] = *(const short8*)((const char*)lsB + swz128((wn + nt*16 + col_l)*128 + kk*64 + rgrp*16));
      #pragma unroll
      for (int mt=0; mt<4; mt++)
        #pragma unroll
        for (int nt=0; nt<4; nt++)
          acc[mt][nt] = mfma16(af[mt], bfr[nt], acc[mt][nt]);
    }
  }
  #pragma unroll
  for (int nt=0; nt<4; nt++){
    int col = n0 + wn + nt*16 + col_l;
    float bb = ga.bias ? ga.bias[col] : 0.0f;
    #pragma unroll
    for (int mt=0; mt<4; mt++){
      #pragma unroll
      for (int r=0; r<4; r++){
        int row = m0 + wm + mt*16 + rgrp*4 + r;
        float v = acc[mt][nt][r] + bb;
        if (ga.act == 1) v = fast_tanh(v);
        ga.C[(size_t)row * ga.ldc + ga.coff + col] = f2bf(v);
      }
    }
  }
}

// ---------------- phase B: tanh-RNN chunk, W_hh held in VGPRs ----------------
__global__ __launch_bounds__(256,1) void rnn_chunk(
    const unsigned short* __restrict__ rnn_in,
    const unsigned short* __restrict__ Whh_t,
    const float* __restrict__ b_hh,
    unsigned short* __restrict__ cat_d,
    float* __restrict__ dn_out,
    unsigned short* __restrict__ d_state,
    int t0, int nsteps)
{
  __shared__ __align__(16) unsigned short dls[16*256];
  const int tid = threadIdx.x, wave = tid >> 6, lane = tid & 63;
  const int col_l = lane & 15, rgrp = lane >> 4;
  const int brow0 = blockIdx.x * 16;
  const int ncol = wave * 64;

  short8 bfr[4][8];
  #pragma unroll
  for (int nt=0; nt<4; nt++){
    const unsigned short* bp = Whh_t + (size_t)(ncol + nt*16 + col_l) * 256;
    #pragma unroll
    for (int kk=0; kk<8; kk++)
      bfr[nt][kk] = *(const short8*)(bp + kk*32 + rgrp*8);
  }
  float bias[4];
  #pragma unroll
  for (int nt=0; nt<4; nt++) bias[nt] = b_hh[ncol + nt*16 + col_l];

  if (t0 == 0){
    for (int i = tid; i < 16*256; i += 256){
      int row = i >> 8, col = i & 255;
      *(unsigned short*)((char*)dls + swz512(row*512 + col*2)) = 0;
    }
  } else {
    const unsigned short* ds = d_state + (size_t)brow0 * 256;
    for (int i = tid; i < 16*256; i += 256){
      int row = i >> 8, col = i & 255;
      *(unsigned short*)((char*)dls + swz512(row*512 + col*2)) = ds[row*256 + col];
    }
  }
  __syncthreads();

  for (int tl=0; tl<nsteps; tl++){
    unsigned short rv[4][4];
    const unsigned short* rp = rnn_in + (size_t)(tl*BATCH + brow0) * 256;
    #pragma unroll
    for (int nt=0; nt<4; nt++)
      #pragma unroll
      for (int r=0; r<4; r++)
        rv[nt][r] = rp[(size_t)(rgrp*4 + r)*256 + ncol + nt*16 + col_l];

    f32x4 acc[4];
    const f32x4 z4 = {0.f,0.f,0.f,0.f};
    acc[0]=z4; acc[1]=z4; acc[2]=z4; acc[3]=z4;
    #pragma unroll
    for (int kk=0; kk<8; kk++){
      short8 af = *(const short8*)((const char*)dls + swz512((lane & 15)*512 + kk*64 + rgrp*16));
      #pragma unroll
      for (int nt=0; nt<4; nt++)
        acc[nt] = mfma16(af, bfr[nt][kk], acc[nt]);
    }
    __syncthreads();
    #pragma unroll
    for (int nt=0; nt<4; nt++){
      #pragma unroll
      for (int r=0; r<4; r++){
        float h = acc[nt][r] + bf2f(rv[nt][r]) + bias[nt];
        float d = fast_tanh(h);
        int row = rgrp*4 + r, col = ncol + nt*16 + col_l;
        unsigned short db = f2bf(d);
        *(unsigned short*)((char*)dls + swz512(row*512 + col*2)) = db;
        cat_d[(size_t)(tl*BATCH + brow0 + row)*512 + col] = db;
        if (t0 + tl == LSEQ-1) dn_out[(size_t)(brow0 + row)*256 + col] = d;
      }
    }
    __syncthreads();
  }
  unsigned short* dso = d_state + (size_t)brow0 * 256;
  for (int i = tid; i < 16*256; i += 256){
    int row = i >> 8, col = i & 255;
    dso[row*256 + col] = *(const unsigned short*)((const char*)dls + swz512(row*512 + col*2));
  }
}

// ---------------- phase D: weight-stationary z recurrence across 4 CUs per group ----------------
// 16 groups x 16 batch rows x 4 roles; 512 threads (8 waves).
// Sync protocol: RELAXED agent atomics only (sc0|sc1, no L2 flush). Ordering:
// producer stores (atomic relaxed) -> __syncthreads (vmcnt drain) -> one flag add;
// readers poll flags (waves 1-3) -> __syncthreads -> atomic relaxed loads.
__global__ __launch_bounds__(512) void zrec_mb(
    const unsigned short* __restrict__ preP1, const unsigned short* __restrict__ preP2,
    const unsigned short* __restrict__ preQ1, const unsigned short* __restrict__ preQ2,
    const unsigned short* __restrict__ Wzz,  // [4 roles][2 mats][256 n][128 k]
    const unsigned short* __restrict__ W2,   // [4 roles][2 mats][128 n][256 k]
    const float* __restrict__ pmub, const float* __restrict__ plsb, const float* __restrict__ qmub,
    const float* __restrict__ eps,
    float* __restrict__ out_mu, float* __restrict__ out_ls, float* __restrict__ out_zn,
    unsigned short* __restrict__ z_state,
    float* __restrict__ mb, int* __restrict__ flags,
    int t0, int nsteps)
{
  __shared__ __align__(16) unsigned short zls[16*128];  // [16][128] stride 256B, swz256
  __shared__ __align__(16) unsigned short tls[16*256];  // [16][256] stride 512B, swz512
  const int tid = threadIdx.x, wave = tid >> 6, lane = tid & 63;
  const int col_l = lane & 15, rgrp = lane >> 4;
  const int bid = blockIdx.x;
  const int c   = (bid >> 3) & 3;                 // role
  const int g   = (bid & 7) + ((bid >> 5) << 3);  // group (XCD-local members)
  const int brow0 = g * 16;
  const int NT2 = (c < 2) ? 2 : 1;

  const unsigned short* pA = (c < 2) ? preP1 : preQ1;
  const unsigned short* pB = (c < 2) ? preP2 : preQ2;
  const int cb = (c & 1) * 256;

  // GEMM1 weights -> VGPRs (64 regs)
  short8 w1[2][2][4];
  {
    const unsigned short* wz = Wzz + (size_t)c * 65536;
    #pragma unroll
    for (int m=0; m<2; m++)
      #pragma unroll
      for (int nt=0; nt<2; nt++){
        int n = wave*32 + nt*16 + col_l;
        #pragma unroll
        for (int kk=0; kk<4; kk++)
          w1[m][nt][kk] = *(const short8*)(wz + (size_t)(m*256 + n)*128 + kk*32 + rgrp*8);
      }
  }
  // GEMM2 weights -> VGPRs (<=64 regs)
  short8 w2r[2][8];
  {
    const unsigned short* wp = W2 + (size_t)c * 65536;
    #pragma unroll
    for (int nt=0; nt<2; nt++){
      if (nt < NT2){
        int ccol = wave*(16*((c<2)?2:1)) + nt*16;
        int mat = (c < 2) ? (ccol >> 7) : 0;
        int n   = (ccol & 127) + col_l;
        #pragma unroll
        for (int kk=0; kk<8; kk++)
          w2r[nt][kk] = *(const short8*)(wp + (size_t)(mat*128 + n)*256 + kk*32 + rgrp*8);
      }
    }
  }
  const int zcol = wave*16 + col_l;   // this thread's z columns (rows rgrp*4+r)
  const float bp = pmub[zcol], bl = plsb[zcol], bq = qmub[zcol];
  int* const myflag = flags + (g*4 + c)*32;

  // init z
  if (t0 == 0){
    for (int i = tid; i < 16*128; i += 512){
      int row = i >> 7, col = i & 127;
      *(unsigned short*)((char*)zls + swz256(row*256 + col*2)) = 0;
    }
  } else {
    const unsigned short* zs = z_state + (size_t)brow0 * 128;
    for (int i = tid; i < 16*128; i += 512){
      int row = i >> 7, col = i & 127;
      *(unsigned short*)((char*)zls + swz256(row*256 + col*2)) = zs[row*128 + col];
    }
  }
  __syncthreads();

  auto LD_PRE = [&](int tl, unsigned short (&pa_)[2][4], unsigned short (&pb_)[2][4]){
    const unsigned short* bA = pA + ((size_t)tl*BATCH + brow0)*512 + cb;
    const unsigned short* bB = pB + ((size_t)tl*BATCH + brow0)*512 + cb;
    #pragma unroll
    for (int nt=0; nt<2; nt++)
      #pragma unroll
      for (int r=0; r<4; r++){
        int row = rgrp*4 + r, col = wave*32 + nt*16 + col_l;
        pa_[nt][r] = bA[(size_t)row*512 + col];
        pb_[nt][r] = bB[(size_t)row*512 + col];
      }
  };

  unsigned short pa0[2][4], pb0[2][4], pa1[2][4], pb1[2][4];
  LD_PRE(0, pa0, pb0);

  const f32x4 z4 = {0.f,0.f,0.f,0.f};
  for (int tl=0; tl<nsteps; ++tl){
    float er[4];
    #pragma unroll
    for (int r=0; r<4; r++){
      size_t grow = (size_t)(t0+tl)*BATCH + brow0 + rgrp*4 + r;
      er[r] = eps[grow*STATE + zcol];
    }
    int nx = (tl+1 < nsteps) ? tl+1 : tl;
    LD_PRE(nx, pa1, pb1);

    // GEMM1: z @ Wf (both mats), K=128
    short8 af1[4];
    #pragma unroll
    for (int kk=0; kk<4; kk++)
      af1[kk] = *(const short8*)((const char*)zls + swz256((lane & 15)*256 + kk*64 + rgrp*16));
    f32x4 a1[2][2];
    a1[0][0]=z4; a1[0][1]=z4; a1[1][0]=z4; a1[1][1]=z4;
    #pragma unroll
    for (int kk=0; kk<4; kk++)
      #pragma unroll
      for (int m=0; m<2; m++)
        #pragma unroll
        for (int nt=0; nt<2; nt++)
          a1[m][nt] = mfma16(af1[kk], w1[m][nt][kk], a1[m][nt]);

    #pragma unroll
    for (int nt=0; nt<2; nt++)
      #pragma unroll
      for (int r=0; r<4; r++){
        float h1 = a1[0][nt][r] + bf2f(pa0[nt][r]);
        float h2 = a1[1][nt][r] + bf2f(pb0[nt][r]);
        float tv = fast_tanh(h1) * fast_sig(h2);
        int row = rgrp*4 + r, tcol = wave*32 + nt*16 + col_l;
        *(unsigned short*)((char*)tls + swz512(row*512 + tcol*2)) = f2bf(tv);
      }
    __syncthreads();

    // GEMM2: t @ Wh (local k-slice), K=256
    f32x4 a2[2];
    a2[0]=z4; a2[1]=z4;
    #pragma unroll
    for (int kk=0; kk<8; kk++){
      short8 af2 = *(const short8*)((const char*)tls + swz512((lane & 15)*512 + kk*64 + rgrp*16));
      #pragma unroll
      for (int nt=0; nt<2; nt++)
        if (nt < NT2) a2[nt] = mfma16(af2, w2r[nt][kk], a2[nt]);
    }
    // publish partial (relaxed agent atomic stores -> coherent point, no cache flush)
    float* slot = mb + ((size_t)(g*2 + (tl & 1))*4 + c)*4096;
    #pragma unroll
    for (int nt=0; nt<2; nt++)
      if (nt < NT2){
        #pragma unroll
        for (int r=0; r<4; r++){
          int ccol = wave*(16*((c<2)?2:1)) + nt*16 + col_l;
          mb_store(&slot[(rgrp*4 + r)*256 + ccol], a2[nt][r]);
        }
      }
    __syncthreads();   // vmcnt(0) drain for all waves' stores
    if (tid == 0)
      __hip_atomic_fetch_add(myflag, 1, __ATOMIC_RELAXED, __HIP_MEMORY_SCOPE_AGENT);

    // waves 1-3 poll one peer each (relaxed loads, no invalidates)
    if (wave >= 1 && wave <= 3 && lane == 0){
      int p = (c + wave) & 3;
      int* pf = flags + (g*4 + p)*32;
      while (__hip_atomic_load(pf, __ATOMIC_RELAXED, __HIP_MEMORY_SCOPE_AGENT) < tl+1)
        __builtin_amdgcn_s_sleep(1);
    }
    __syncthreads();

    // reduce partials -> mu, ls, z (redundant on all roles; identical fp order)
    const float* mbb = mb + (size_t)(g*2 + (tl & 1))*4*4096;
    #pragma unroll
    for (int r=0; r<4; r++){
      int row = rgrp*4 + r;
      const float* r0 = mbb + row*256;
      float mup = mb_load(&r0[zcol])          + mb_load(&r0[4096 + zcol]);
      float lsp = mb_load(&r0[128 + zcol])    + mb_load(&r0[4096 + 128 + zcol]);
      float muq = mb_load(&r0[2*4096 + zcol]) + mb_load(&r0[3*4096 + zcol]);
      float mu  = (muq + bq) + (mup + bp);
      float ls  = lsp + bl;
      float z   = mu + __expf(0.5f * ls) * er[r];
      *(unsigned short*)((char*)zls + swz256(row*256 + zcol*2)) = f2bf(z);
      if (c == 0){
        size_t grow = (size_t)(t0+tl)*BATCH + brow0 + row;
        out_mu[grow*STATE + zcol] = mu;
        out_ls[grow*STATE + zcol] = ls;
        if (t0 + tl == LSEQ-1) out_zn[((size_t)(brow0 + row))*STATE + zcol] = z;
      }
    }
    __syncthreads();

    #pragma unroll
    for (int nt=0; nt<2; nt++)
      #pragma unroll
      for (int r=0; r<4; r++){ pa0[nt][r] = pa1[nt][r]; pb0[nt][r] = pb1[nt][r]; }
  }

  // persist z state (role 0 writes)
  if (c == 0){
    unsigned short* zso = z_state + (size_t)brow0 * 128;
    for (int i = tid; i < 16*128; i += 512){
      int row = i >> 7, col = i & 127;
      zso[row*128 + col] = *(const unsigned short*)((const char*)zls + swz256(row*256 + col*2));
    }
  }
}

// ---------------- host launcher ----------------
extern "C" void kernel_launch(void* const* d_in, const int* in_sizes, int n_in,
                              void* d_out, int out_size, void* d_ws, size_t ws_size,
                              hipStream_t stream)
{
  const float* ext = (const float*)d_in[0];
  const float* obs = (const float*)d_in[1];
  const float* eps = (const float*)d_in[2];
  const float* Wu  = (const float*)d_in[3];
  const float* bu  = (const float*)d_in[4];
  const float* Wx  = (const float*)d_in[5];
  const float* bx  = (const float*)d_in[6];
  const float* W_ih= (const float*)d_in[7];
  const float* b_ih= (const float*)d_in[8];
  const float* W_hh= (const float*)d_in[9];
  const float* b_hh= (const float*)d_in[10];
  const float* Wa1 = (const float*)d_in[11];
  const float* ba1 = (const float*)d_in[12];
  const float* Wa2 = (const float*)d_in[13];
  const float* ba2 = (const float*)d_in[14];
  const float* pf1W= (const float*)d_in[15]; const float* pf1b = (const float*)d_in[16];
  const float* pf2W= (const float*)d_in[17]; const float* pf2b = (const float*)d_in[18];
  const float* pmuW= (const float*)d_in[19]; const float* pmub = (const float*)d_in[20];
  const float* plsW= (const float*)d_in[21]; const float* plsb = (const float*)d_in[22];
  const float* qf1W= (const float*)d_in[23]; const float* qf1b = (const float*)d_in[24];
  const float* qf2W= (const float*)d_in[25]; const float* qf2b = (const float*)d_in[26];
  const float* qmuW= (const float*)d_in[27]; const float* qmub = (const float*)d_in[28];

  int NC = 0;
  const int cands[7] = {1,2,4,8,16,32,64};
  size_t rows = 0;
  for (int ci=0; ci<7; ci++){
    size_t r = (size_t)(LSEQ/cands[ci])*BATCH;
    size_t elems = 2700000 + r*3072;
    if (elems * 2 <= ws_size){ NC = cands[ci]; rows = r; break; }
  }
  if (!NC) return;
  const int nsteps = LSEQ/NC;
  const int gx = (int)(rows/128);

  unsigned short* ws = (unsigned short*)d_ws;
  size_t off = 0;
  auto alloc = [&](size_t elems){
    unsigned short* p = ws + off;
    off += (elems + 127) & ~(size_t)127;
    return p;
  };

  unsigned short* Wu_t  = alloc(64*256);
  unsigned short* Wx_t  = alloc(64*256);
  unsigned short* Wih_t = alloc(256*256);
  unsigned short* Whh_t = alloc(256*256);
  unsigned short* Wa1_t = alloc(512*256);
  unsigned short* Wa2_t = alloc(256*256);
  unsigned short* f1a_p = alloc(256*512);
  unsigned short* f2a_p = alloc(256*512);
  unsigned short* f1a_q = alloc(256*512);
  unsigned short* f2a_q = alloc(256*512);
  unsigned short* Wzz   = alloc(4*2*256*128);  // [role][mat][n][k]
  unsigned short* W2z   = alloc(4*2*128*256);  // [role][mat][n][k]
  unsigned short* d_state = alloc(256*256);
  unsigned short* z_state = alloc(256*128);
  float* mbx  = (float*)alloc(2*16*2*4*4096); // 16 groups x 2 parity x 4 roles x 4096 f32
  int*   flg  = (int*)alloc(2*2048);          // 16x4 flags, 32-int stride
  unsigned short* bufA  = alloc(rows*256);
  unsigned short* bufB  = alloc(rows*256);
  unsigned short* bufC  = alloc(rows*512);
  unsigned short* preP1 = alloc(rows*512);
  unsigned short* preP2 = alloc(rows*512);
  unsigned short* preQ1 = alloc(rows*512);
  unsigned short* preQ2 = alloc(rows*512);
  if (off * sizeof(unsigned short) > ws_size) return;

  float* out_mu = (float*)d_out;
  float* out_ls = out_mu + (size_t)LSEQ*BATCH*STATE;
  float* out_dn = out_ls + (size_t)LSEQ*BATCH*STATE;
  float* out_zn = out_dn + (size_t)BATCH*KDIM;

  WDescs wd;
  int wi = 0;
  auto add = [&](const float* s, unsigned short* d, int Kk, int Nn, int ld, int ro, int co){
    wd.d[wi].src = s; wd.d[wi].dst = d; wd.d[wi].K = Kk; wd.d[wi].N = Nn;
    wd.d[wi].ld = ld; wd.d[wi].rowoff = ro; wd.d[wi].coloff = co; wi++;
  };
  add(Wu,   Wu_t,  64, 256, 256, 0, 0);
  add(Wx,   Wx_t,  64, 256, 256, 0, 0);
  add(W_ih, Wih_t, 256, 256, 256, 0, 0);
  add(W_hh, Whh_t, 256, 256, 256, 0, 0);
  add(Wa1,  Wa1_t, 512, 256, 256, 0, 0);
  add(Wa2,  Wa2_t, 256, 256, 256, 0, 0);
  add(pf1W, f1a_p, 256, 512, 512, 128, 0);
  add(pf2W, f2a_p, 256, 512, 512, 128, 0);
  add(qf1W, f1a_q, 256, 512, 512, 128, 0);
  add(qf2W, f2a_q, 256, 512, 512, 128, 0);
  for (int c=0; c<4; c++){
    const float* s1 = (c < 2) ? pf1W : qf1W;
    const float* s2 = (c < 2) ? pf2W : qf2W;
    add(s1, Wzz + (size_t)(c*2+0)*32768, 128, 256, 512, 0, (c&1)*256);
    add(s2, Wzz + (size_t)(c*2+1)*32768, 128, 256, 512, 0, (c&1)*256);
  }
  add(pmuW, W2z + (size_t)(0*2+0)*32768, 256, 128, 128, 0,   0);
  add(plsW, W2z + (size_t)(0*2+1)*32768, 256, 128, 128, 0,   0);
  add(pmuW, W2z + (size_t)(1*2+0)*32768, 256, 128, 128, 256, 0);
  add(plsW, W2z + (size_t)(1*2+1)*32768, 256, 128, 128, 256, 0);
  add(qmuW, W2z + (size_t)(2*2+0)*32768, 256, 128, 128, 0,   0);
  add(qmuW, W2z + (size_t)(3*2+0)*32768, 256, 128, 128, 256, 0);

  convert_weights<<<dim3(512,24), 256, 0, stream>>>(wd);

  for (int c=0; c<NC; ++c){
    const int t0 = c * nsteps;
    const size_t row0 = (size_t)t0 * BATCH;

    GArgs e{};
    e.g[0] = GArg{ext + row0*64, Wu_t, bu, bufA, 64, 256, 0,   64, 1, 1};
    e.g[1] = GArg{obs + row0*64, Wx_t, bx, bufC, 64, 512, 256, 64, 1, 1};
    gemm_multi<<<dim3(gx,2,2), 256, 0, stream>>>(e);

    GArgs rn{};
    rn.g[0] = GArg{bufA, Wih_t, b_ih, bufB, 256, 256, 0, 256, 0, 0};
    gemm_multi<<<dim3(gx,2,1), 256, 0, stream>>>(rn);

    rnn_chunk<<<16, 256, 0, stream>>>(bufB, Whh_t, b_hh, bufC, out_dn, d_state, t0, nsteps);

    GArgs a1{};
    a1.g[0] = GArg{bufC, Wa1_t, ba1, bufA, 512, 256, 0, 512, 1, 0};
    gemm_multi<<<dim3(gx,2,1), 256, 0, stream>>>(a1);

    GArgs a2{};
    a2.g[0] = GArg{bufA, Wa2_t, ba2, bufB, 256, 256, 0, 256, 0, 0};
    gemm_multi<<<dim3(gx,2,1), 256, 0, stream>>>(a2);

    GArgs pr{};
    pr.g[0] = GArg{bufB, f1a_p, pf1b, preP1, 256, 512, 0, 256, 0, 0};
    pr.g[1] = GArg{bufB, f2a_p, pf2b, preP2, 256, 512, 0, 256, 0, 0};
    pr.g[2] = GArg{bufC, f1a_q, qf1b, preQ1, 512, 512, 0, 256, 0, 0};
    pr.g[3] = GArg{bufC, f2a_q, qf2b, preQ2, 512, 512, 0, 256, 0, 0};
    gemm_multi<<<dim3(gx,4,4), 256, 0, stream>>>(pr);

    init_flags<<<8, 256, 0, stream>>>(flg);
    zrec_mb<<<64, 512, 0, stream>>>(preP1, preP2, preQ1, preQ2, Wzz, W2z,
                                    pmub, plsb, qmub, eps, out_mu, out_ls, out_zn,
                                    z_state, mbx, flg, t0, nsteps);
  }
}

// Round 6
// 3901.991 us; speedup vs baseline: 4.7619x; 1.0198x over previous
//
#include <hip/hip_runtime.h>

#define LSEQ 512
#define BATCH 256
#define KDIM 256
#define STATE 128

using f32x4  = __attribute__((ext_vector_type(4))) float;
using short8 = __attribute__((ext_vector_type(8))) short;
using u32x2  = __attribute__((ext_vector_type(2))) unsigned int;
using u32x4  = __attribute__((ext_vector_type(4))) unsigned int;

__device__ __forceinline__ float bf2f(unsigned short u){
  return __uint_as_float(((unsigned int)u) << 16);
}
__device__ __forceinline__ unsigned short f2bf(float f){
  unsigned int u = __float_as_uint(f);
  u += 0x7FFFu + ((u >> 16) & 1u);   // RNE
  return (unsigned short)(u >> 16);
}
__device__ __forceinline__ float fast_tanh(float x){
  float ax = fabsf(x);
  float e  = __expf(2.0f * ax);
  float t  = 1.0f - 2.0f / (e + 1.0f);
  return copysignf(t, x);
}
__device__ __forceinline__ float fast_sig(float x){
  return 1.0f / (1.0f + __expf(-x));
}
__device__ __forceinline__ f32x4 mfma16(short8 a, short8 b, f32x4 c){
  return __builtin_amdgcn_mfma_f32_16x16x32_bf16(a, b, c, 0, 0, 0);
}

__device__ __forceinline__ int swz128 (int b){ return b ^ ((((b >> 7) & 7) << 4)); }
__device__ __forceinline__ int swz256 (int b){ return b ^ ((((b >> 8) & 7) << 4)); }
__device__ __forceinline__ int swz512 (int b){ return b ^ ((((b >> 9) & 7) << 4)); }

// ---- Infinity-Cache-scope accessors (sc0 sc1: bypass L1+L2, coherent on any
// XCD placement). NO acquire/release -> no cache-flush ops. Ordering built
// manually: data stores -> vmcnt(0) -> barrier -> flag store; readers poll
// flag, barrier, then sc0sc1 loads.
__device__ __forceinline__ void st_b128_ic(void* p, u32x4 v){
  asm volatile("global_store_dwordx4 %0, %1, off sc0 sc1" :: "v"(p), "v"(v) : "memory");
}
__device__ __forceinline__ void st_b64_ic(void* p, u32x2 v){
  asm volatile("global_store_dwordx2 %0, %1, off sc0 sc1" :: "v"(p), "v"(v) : "memory");
}
#define LD2_IC(dst, p) asm volatile("global_load_dwordx2 %0, %1, off sc0 sc1" : "=v"(dst) : "v"(p) : "memory")

__device__ __forceinline__ f32x4 cvt4(u32x2 q){
  f32x4 r;
  r[0] = __uint_as_float(q[0] << 16);
  r[1] = __uint_as_float(q[0] & 0xFFFF0000u);
  r[2] = __uint_as_float(q[1] << 16);
  r[3] = __uint_as_float(q[1] & 0xFFFF0000u);
  return r;
}

// ---------------- weight convert: f32 src[rowoff+k][coloff+n] -> bf16 dst[n*K+k] ----------------
struct WDesc { const float* src; unsigned short* dst; int K, N, ld, rowoff, coloff; };
struct WDescs { WDesc d[24]; };

__global__ __launch_bounds__(256,4) void convert_weights(WDescs ds){
  WDesc w = ds.d[blockIdx.y];
  int total = w.K * w.N;
  int idx = blockIdx.x * 256 + threadIdx.x;
  if (idx < total){
    int n = idx / w.K;
    int k = idx - n * w.K;
    w.dst[idx] = f2bf(w.src[(size_t)(w.rowoff + k) * w.ld + w.coloff + n]);
  }
}

__global__ __launch_bounds__(256,1) void init_flags(int* flags){
  flags[blockIdx.x * 256 + threadIdx.x] = 0;
}

// ---------------- multi-descriptor bf16 MFMA GEMM ----------------
struct GArg {
  const void* A; const unsigned short* Bt; const float* bias; const float* bias2;
  unsigned short* C; int lda, ldc, coff, K, act, a_f32;
};
struct GArgs { GArg g[4]; };

__global__ __launch_bounds__(256,2) void gemm_multi(GArgs args){
  GArg ga = args.g[blockIdx.z];
  __shared__ __align__(16) unsigned short lsA[128*64];
  __shared__ __align__(16) unsigned short lsB[128*64];
  const int tid  = threadIdx.x;
  const int wave = tid >> 6, lane = tid & 63;
  const int col_l = lane & 15, rgrp = lane >> 4;
  const int m0 = blockIdx.x * 128, n0 = blockIdx.y * 128;
  const int wm = (wave >> 1) * 64, wn = (wave & 1) * 64;

  f32x4 acc[4][4];
  const f32x4 z4 = {0.f,0.f,0.f,0.f};
  #pragma unroll
  for (int i=0;i<4;i++){ acc[i][0]=z4; acc[i][1]=z4; acc[i][2]=z4; acc[i][3]=z4; }

  const int srow = tid >> 1;
  const int sbe  = (tid & 1) * 32;

  for (int k0 = 0; k0 < ga.K; k0 += 64){
    uint4 av[4], bv[4];
    if (ga.a_f32){
      const float* Ap = (const float*)ga.A + (size_t)(m0 + srow) * ga.lda + k0 + sbe;
      uint4 fv[8];
      #pragma unroll
      for (int i=0;i<8;i++) fv[i] = *(const uint4*)((const char*)Ap + i*16);
      #pragma unroll
      for (int i=0;i<4;i++){
        const float* f = (const float*)&fv[i*2];
        uint4 o;
        o.x = (unsigned)f2bf(f[0]) | ((unsigned)f2bf(f[1]) << 16);
        o.y = (unsigned)f2bf(f[2]) | ((unsigned)f2bf(f[3]) << 16);
        o.z = (unsigned)f2bf(f[4]) | ((unsigned)f2bf(f[5]) << 16);
        o.w = (unsigned)f2bf(f[6]) | ((unsigned)f2bf(f[7]) << 16);
        av[i] = o;
      }
    } else {
      const unsigned short* Ap = (const unsigned short*)ga.A + (size_t)(m0 + srow) * ga.lda + k0 + sbe;
      #pragma unroll
      for (int i=0;i<4;i++) av[i] = *(const uint4*)((const char*)Ap + i*16);
    }
    const unsigned short* Bp = ga.Bt + (size_t)(n0 + srow) * ga.K + k0 + sbe;
    #pragma unroll
    for (int i=0;i<4;i++) bv[i] = *(const uint4*)((const char*)Bp + i*16);

    __syncthreads();
    #pragma unroll
    for (int i=0;i<4;i++){
      *(uint4*)((char*)lsA + swz128(srow*128 + sbe*2 + i*16)) = av[i];
      *(uint4*)((char*)lsB + swz128(srow*128 + sbe*2 + i*16)) = bv[i];
    }
    __syncthreads();
    #pragma unroll
    for (int kk=0; kk<2; kk++){
      short8 af[4], bfr[4];
      #pragma unroll
      for (int mt=0; mt<4; mt++)
        af[mt] = *(const short8*)((const char*)lsA + swz128((wm + mt*16 + col_l)*128 + kk*64 + rgrp*16));
      #pragma unroll
      for (int nt=0; nt<4; nt++)
        bfr[nt] = *(const short8*)((const char*)lsB + swz128((wn + nt*16 + col_l)*128 + kk*64 + rgrp*16));
      #pragma unroll
      for (int mt=0; mt<4; mt++)
        #pragma unroll
        for (int nt=0; nt<4; nt++)
          acc[mt][nt] = mfma16(af[mt], bfr[nt], acc[mt][nt]);
    }
  }
  #pragma unroll
  for (int nt=0; nt<4; nt++){
    int col = n0 + wn + nt*16 + col_l;
    const float* bsrc = (col < 512) ? ga.bias : ga.bias2;
    float bb = bsrc ? bsrc[col & 511] : 0.0f;
    #pragma unroll
    for (int mt=0; mt<4; mt++){
      #pragma unroll
      for (int r=0; r<4; r++){
        int row = m0 + wm + mt*16 + rgrp*4 + r;
        float v = acc[mt][nt][r] + bb;
        if (ga.act == 1) v = fast_tanh(v);
        ga.C[(size_t)row * ga.ldc + ga.coff + col] = f2bf(v);
      }
    }
  }
}

// ---------------- phase B: tanh-RNN chunk, W_hh held in VGPRs ----------------
__global__ __launch_bounds__(256,1) void rnn_chunk(
    const unsigned short* __restrict__ rnn_in,
    const unsigned short* __restrict__ Whh_t,
    const float* __restrict__ b_hh,
    unsigned short* __restrict__ cat_d,
    float* __restrict__ dn_out,
    unsigned short* __restrict__ d_state,
    int t0, int nsteps)
{
  __shared__ __align__(16) unsigned short dls[16*256];
  const int tid = threadIdx.x, wave = tid >> 6, lane = tid & 63;
  const int col_l = lane & 15, rgrp = lane >> 4;
  const int brow0 = blockIdx.x * 16;
  const int ncol = wave * 64;

  short8 bfr[4][8];
  #pragma unroll
  for (int nt=0; nt<4; nt++){
    const unsigned short* bp = Whh_t + (size_t)(ncol + nt*16 + col_l) * 256;
    #pragma unroll
    for (int kk=0; kk<8; kk++)
      bfr[nt][kk] = *(const short8*)(bp + kk*32 + rgrp*8);
  }
  float bias[4];
  #pragma unroll
  for (int nt=0; nt<4; nt++) bias[nt] = b_hh[ncol + nt*16 + col_l];

  if (t0 == 0){
    for (int i = tid; i < 16*256; i += 256){
      int row = i >> 8, col = i & 255;
      *(unsigned short*)((char*)dls + swz512(row*512 + col*2)) = 0;
    }
  } else {
    const unsigned short* ds = d_state + (size_t)brow0 * 256;
    for (int i = tid; i < 16*256; i += 256){
      int row = i >> 8, col = i & 255;
      *(unsigned short*)((char*)dls + swz512(row*512 + col*2)) = ds[row*256 + col];
    }
  }
  __syncthreads();

  for (int tl=0; tl<nsteps; tl++){
    unsigned short rv[4][4];
    const unsigned short* rp = rnn_in + (size_t)(tl*BATCH + brow0) * 256;
    #pragma unroll
    for (int nt=0; nt<4; nt++)
      #pragma unroll
      for (int r=0; r<4; r++)
        rv[nt][r] = rp[(size_t)(rgrp*4 + r)*256 + ncol + nt*16 + col_l];

    f32x4 acc[4];
    const f32x4 z4 = {0.f,0.f,0.f,0.f};
    acc[0]=z4; acc[1]=z4; acc[2]=z4; acc[3]=z4;
    #pragma unroll
    for (int kk=0; kk<8; kk++){
      short8 af = *(const short8*)((const char*)dls + swz512((lane & 15)*512 + kk*64 + rgrp*16));
      #pragma unroll
      for (int nt=0; nt<4; nt++)
        acc[nt] = mfma16(af, bfr[nt][kk], acc[nt]);
    }
    __syncthreads();
    #pragma unroll
    for (int nt=0; nt<4; nt++){
      #pragma unroll
      for (int r=0; r<4; r++){
        float h = acc[nt][r] + bf2f(rv[nt][r]) + bias[nt];
        float d = fast_tanh(h);
        int row = rgrp*4 + r, col = ncol + nt*16 + col_l;
        unsigned short db = f2bf(d);
        *(unsigned short*)((char*)dls + swz512(row*512 + col*2)) = db;
        cat_d[(size_t)(tl*BATCH + brow0 + row)*512 + col] = db;
        if (t0 + tl == LSEQ-1) dn_out[(size_t)(brow0 + row)*256 + col] = d;
      }
    }
    __syncthreads();
  }
  unsigned short* dso = d_state + (size_t)brow0 * 256;
  for (int i = tid; i < 16*256; i += 256){
    int row = i >> 8, col = i & 255;
    dso[row*256 + col] = *(const unsigned short*)((const char*)dls + swz512(row*512 + col*2));
  }
}

// ---------------- phase D: weight-stationary z recurrence, IC mailbox (pure) ----------------
// 16 groups x 16 batch rows x 4 roles; 512 threads (8 waves). Protocol identical
// in structure to the proven r4 version; optimized transactions:
// bf16 partials, LDS-bounce -> single x4 IC store/thread, x2 vector reads,
// single-wave lane-parallel polling.
__global__ __launch_bounds__(512,1) void zrec_mb(
    const unsigned short* __restrict__ preP, const unsigned short* __restrict__ preQ, // [ns*B,1024]
    const unsigned short* __restrict__ Wzz,  // [4 roles][2 mats][256 n][128 k]
    const unsigned short* __restrict__ W2,   // [4 roles][2 mats][128 n][256 k]
    const float* __restrict__ pmub, const float* __restrict__ plsb, const float* __restrict__ qmub,
    const float* __restrict__ eps,
    float* __restrict__ out_mu, float* __restrict__ out_ls, float* __restrict__ out_zn,
    unsigned short* __restrict__ z_state,
    unsigned short* __restrict__ mb, int* __restrict__ flags,
    int t0, int nsteps, int fbase)
{
  __shared__ __align__(16) unsigned short zls[16*128];  // z, stride 256B, swz256
  __shared__ __align__(16) unsigned short tls[16*256];  // t (swz512) / publish bounce (linear)
  const int tid = threadIdx.x, wave = tid >> 6, lane = tid & 63;
  const int col_l = lane & 15, rgrp = lane >> 4;
  const int bid = blockIdx.x;
  const int c   = (bid >> 3) & 3;                 // role
  const int g   = (bid & 7) + ((bid >> 5) << 3);  // group
  const int brow0 = g * 16;
  const int NT2 = (c < 2) ? 2 : 1;

  const unsigned short* pre = (c < 2) ? preP : preQ;
  const int cb = (c & 1) * 256;

  // GEMM1 weights -> registers
  short8 w1[2][2][4];
  {
    const unsigned short* wz = Wzz + (size_t)c * 65536;
    #pragma unroll
    for (int m=0; m<2; m++)
      #pragma unroll
      for (int nt=0; nt<2; nt++){
        int n = wave*32 + nt*16 + col_l;
        #pragma unroll
        for (int kk=0; kk<4; kk++)
          w1[m][nt][kk] = *(const short8*)(wz + (size_t)(m*256 + n)*128 + kk*32 + rgrp*8);
      }
  }
  // GEMM2 weights -> registers
  short8 w2r[2][8];
  {
    const unsigned short* wp = W2 + (size_t)c * 65536;
    #pragma unroll
    for (int nt=0; nt<2; nt++){
      if (nt < NT2){
        int ccol = wave*(16*((c<2)?2:1)) + nt*16;
        int mat = (c < 2) ? (ccol >> 7) : 0;
        int n   = (ccol & 127) + col_l;
        #pragma unroll
        for (int kk=0; kk<8; kk++)
          w2r[nt][kk] = *(const short8*)(wp + (size_t)(mat*128 + n)*256 + kk*32 + rgrp*8);
      }
    }
  }
  int* const myflag = flags + (g*4 + c)*32;

  // init z
  if (t0 == 0){
    for (int i = tid; i < 16*128; i += 512){
      int row = i >> 7, col = i & 127;
      *(unsigned short*)((char*)zls + swz256(row*256 + col*2)) = 0;
    }
  } else {
    const unsigned short* zs = z_state + (size_t)brow0 * 128;
    for (int i = tid; i < 16*128; i += 512){
      int row = i >> 7, col = i & 127;
      *(unsigned short*)((char*)zls + swz256(row*256 + col*2)) = zs[row*128 + col];
    }
  }
  __syncthreads();

  auto LD_PRE = [&](int tl, unsigned short (&pa_)[2][4], unsigned short (&pb_)[2][4]){
    const unsigned short* bA = pre + ((size_t)tl*BATCH + brow0)*1024 + cb;
    #pragma unroll
    for (int nt=0; nt<2; nt++)
      #pragma unroll
      for (int r=0; r<4; r++){
        int row = rgrp*4 + r, col = wave*32 + nt*16 + col_l;
        pa_[nt][r] = bA[(size_t)row*1024 + col];
        pb_[nt][r] = bA[(size_t)row*1024 + 512 + col];
      }
  };

  // reduce-phase mapping: thread -> (row, 4 consecutive z-cols)
  const int rrow = tid >> 5;
  const int rc0  = (tid & 31) * 4;
  const f32x4 bp4 = *(const f32x4*)(pmub + rc0);
  const f32x4 bl4 = *(const f32x4*)(plsb + rc0);
  const f32x4 bq4 = *(const f32x4*)(qmub + rc0);

  unsigned short pa0[2][4], pb0[2][4], pa1[2][4], pb1[2][4];
  LD_PRE(0, pa0, pb0);

  const f32x4 z4 = {0.f,0.f,0.f,0.f};
  for (int tl=0; tl<nsteps; ++tl){
    size_t growr = (size_t)(t0+tl)*BATCH + brow0 + rrow;
    f32x4 er = *(const f32x4*)(eps + growr*STATE + rc0);
    int nx = (tl+1 < nsteps) ? tl+1 : tl;
    LD_PRE(nx, pa1, pb1);

    // GEMM1: z @ Wf (both mats), K=128
    short8 af1[4];
    #pragma unroll
    for (int kk=0; kk<4; kk++)
      af1[kk] = *(const short8*)((const char*)zls + swz256((lane & 15)*256 + kk*64 + rgrp*16));
    f32x4 a1[2][2];
    a1[0][0]=z4; a1[0][1]=z4; a1[1][0]=z4; a1[1][1]=z4;
    #pragma unroll
    for (int kk=0; kk<4; kk++)
      #pragma unroll
      for (int m=0; m<2; m++)
        #pragma unroll
        for (int nt=0; nt<2; nt++)
          a1[m][nt] = mfma16(af1[kk], w1[m][nt][kk], a1[m][nt]);

    #pragma unroll
    for (int nt=0; nt<2; nt++)
      #pragma unroll
      for (int r=0; r<4; r++){
        float h1 = a1[0][nt][r] + bf2f(pa0[nt][r]);
        float h2 = a1[1][nt][r] + bf2f(pb0[nt][r]);
        float tv = fast_tanh(h1) * fast_sig(h2);
        int row = rgrp*4 + r, tcol = wave*32 + nt*16 + col_l;
        *(unsigned short*)((char*)tls + swz512(row*512 + tcol*2)) = f2bf(tv);
      }
    __syncthreads();

    // GEMM2: t @ Wh (local k-slice), K=256
    f32x4 a2[2];
    a2[0]=z4; a2[1]=z4;
    #pragma unroll
    for (int kk=0; kk<8; kk++){
      short8 af2 = *(const short8*)((const char*)tls + swz512((lane & 15)*512 + kk*64 + rgrp*16));
      #pragma unroll
      for (int nt=0; nt<2; nt++)
        if (nt < NT2) a2[nt] = mfma16(af2, w2r[nt][kk], a2[nt]);
    }
    __syncthreads();   // tls reads done -> reuse as publish bounce (linear bf16)

    if (c < 2){
      #pragma unroll
      for (int nt=0; nt<2; nt++)
        #pragma unroll
        for (int r=0; r<4; r++)
          tls[(rgrp*4 + r)*256 + wave*32 + nt*16 + col_l] = f2bf(a2[nt][r]);
    } else {
      #pragma unroll
      for (int r=0; r<4; r++)
        tls[(rgrp*4 + r)*128 + wave*16 + col_l] = f2bf(a2[0][r]);
    }
    __syncthreads();

    // packed publish: one vector IC store per thread
    unsigned short* slot = mb + (size_t)((g*2 + (tl & 1))*4 + c)*4096;
    if (c < 2){
      u32x4 v = *(const u32x4*)((const char*)tls + tid*16);
      st_b128_ic(slot + tid*8, v);
    } else {
      u32x2 v = *(const u32x2*)((const char*)tls + tid*8);
      st_b64_ic(slot + tid*4, v);
    }
    asm volatile("s_waitcnt vmcnt(0)" ::: "memory");   // this wave's store complete
    __syncthreads();                                    // all waves' stores complete
    const int target = fbase + tl + 1;
    if (tid == 0)
      __hip_atomic_store(myflag, target, __ATOMIC_RELAXED, __HIP_MEMORY_SCOPE_AGENT);

    // wave 7: lanes 0-2 poll the three peers (one load polls all)
    if (wave == 7 && lane < 3){
      const int* pf = flags + (g*4 + ((c + 1 + lane) & 3))*32;
      while (__hip_atomic_load(pf, __ATOMIC_RELAXED, __HIP_MEMORY_SCOPE_AGENT) < target)
        __builtin_amdgcn_s_sleep(1);
    }
    __syncthreads();

    // reduce partials (bf16) -> mu, ls, z (redundant on all roles; identical fp order)
    const unsigned short* mbb = mb + (size_t)((g*2 + (tl & 1))*4)*4096;
    const unsigned short* s0 = mbb;
    const unsigned short* s1 = mbb + 4096;
    const unsigned short* s2 = mbb + 8192;
    const unsigned short* s3 = mbb + 12288;
    u32x2 q0,q1,q2,q3,q4,q5;
    LD2_IC(q0, s0 + rrow*256 + rc0);
    LD2_IC(q1, s1 + rrow*256 + rc0);
    LD2_IC(q2, s0 + rrow*256 + 128 + rc0);
    LD2_IC(q3, s1 + rrow*256 + 128 + rc0);
    LD2_IC(q4, s2 + rrow*128 + rc0);
    LD2_IC(q5, s3 + rrow*128 + rc0);
    asm volatile("s_waitcnt vmcnt(0)" ::: "memory");
    __builtin_amdgcn_sched_barrier(0);

    f32x4 mup = cvt4(q0) + cvt4(q1);
    f32x4 lsv = cvt4(q2) + cvt4(q3) + bl4;
    f32x4 muq = cvt4(q4) + cvt4(q5);
    f32x4 muv = (muq + bq4) + (mup + bp4);
    f32x4 zv;
    #pragma unroll
    for (int i=0; i<4; i++) zv[i] = muv[i] + __expf(0.5f * lsv[i]) * er[i];

    unsigned int lo = (unsigned)f2bf(zv[0]) | ((unsigned)f2bf(zv[1]) << 16);
    unsigned int hi = (unsigned)f2bf(zv[2]) | ((unsigned)f2bf(zv[3]) << 16);
    uint2 zp; zp.x = lo; zp.y = hi;
    *(uint2*)((char*)zls + swz256(rrow*256 + rc0*2)) = zp;
    if (c == 0){
      *(f32x4*)(out_mu + growr*STATE + rc0) = muv;
      *(f32x4*)(out_ls + growr*STATE + rc0) = lsv;
      if (t0 + tl == LSEQ-1)
        *(f32x4*)(out_zn + ((size_t)(brow0 + rrow))*STATE + rc0) = zv;
    }
    __syncthreads();

    #pragma unroll
    for (int nt=0; nt<2; nt++)
      #pragma unroll
      for (int r=0; r<4; r++){ pa0[nt][r] = pa1[nt][r]; pb0[nt][r] = pb1[nt][r]; }
  }

  // persist z state (role 0 writes)
  if (c == 0){
    unsigned short* zso = z_state + (size_t)brow0 * 128;
    for (int i = tid; i < 16*128; i += 512){
      int row = i >> 7, col = i & 127;
      zso[row*128 + col] = *(const unsigned short*)((const char*)zls + swz256(row*256 + col*2));
    }
  }
}

// ---------------- host launcher ----------------
extern "C" void kernel_launch(void* const* d_in, const int* in_sizes, int n_in,
                              void* d_out, int out_size, void* d_ws, size_t ws_size,
                              hipStream_t stream)
{
  const float* ext = (const float*)d_in[0];
  const float* obs = (const float*)d_in[1];
  const float* eps = (const float*)d_in[2];
  const float* Wu  = (const float*)d_in[3];
  const float* bu  = (const float*)d_in[4];
  const float* Wx  = (const float*)d_in[5];
  const float* bx  = (const float*)d_in[6];
  const float* W_ih= (const float*)d_in[7];
  const float* b_ih= (const float*)d_in[8];
  const float* W_hh= (const float*)d_in[9];
  const float* b_hh= (const float*)d_in[10];
  const float* Wa1 = (const float*)d_in[11];
  const float* ba1 = (const float*)d_in[12];
  const float* Wa2 = (const float*)d_in[13];
  const float* ba2 = (const float*)d_in[14];
  const float* pf1W= (const float*)d_in[15]; const float* pf1b = (const float*)d_in[16];
  const float* pf2W= (const float*)d_in[17]; const float* pf2b = (const float*)d_in[18];
  const float* pmuW= (const float*)d_in[19]; const float* pmub = (const float*)d_in[20];
  const float* plsW= (const float*)d_in[21]; const float* plsb = (const float*)d_in[22];
  const float* qf1W= (const float*)d_in[23]; const float* qf1b = (const float*)d_in[24];
  const float* qf2W= (const float*)d_in[25]; const float* qf2b = (const float*)d_in[26];
  const float* qmuW= (const float*)d_in[27]; const float* qmub = (const float*)d_in[28];

  int NC = 0;
  const int cands[7] = {1,2,4,8,16,32,64};
  size_t rows = 0;
  for (int ci=0; ci<7; ci++){
    size_t r = (size_t)(LSEQ/cands[ci])*BATCH;
    size_t elems = 2700000 + r*3072;
    if (elems * 2 <= ws_size){ NC = cands[ci]; rows = r; break; }
  }
  if (!NC) return;
  const int nsteps = LSEQ/NC;
  const int gx = (int)(rows/128);

  unsigned short* ws = (unsigned short*)d_ws;
  size_t off = 0;
  auto alloc = [&](size_t elems){
    unsigned short* p = ws + off;
    off += (elems + 127) & ~(size_t)127;
    return p;
  };

  unsigned short* Wu_t  = alloc(64*256);
  unsigned short* Wx_t  = alloc(64*256);
  unsigned short* Wih_t = alloc(256*256);
  unsigned short* Whh_t = alloc(256*256);
  unsigned short* Wa1_t = alloc(512*256);
  unsigned short* Wa2_t = alloc(256*256);
  unsigned short* fAp   = alloc(1024*256);     // [f1(512) | f2(512)] x [256 k]
  unsigned short* fAq   = alloc(1024*256);
  unsigned short* Wzz   = alloc(4*2*256*128);  // [role][mat][n][k]
  unsigned short* W2z   = alloc(4*2*128*256);  // [role][mat][n][k]
  unsigned short* d_state = alloc(256*256);
  unsigned short* z_state = alloc(256*128);
  unsigned short* mbx  = alloc(16*2*4*4096);   // bf16 mailbox: 16g x 2par x 4roles x 4096
  int*   flg  = (int*)alloc(4096);             // 2048 ints of flags (64 used, 128B stride)
  unsigned short* bufA  = alloc(rows*256);
  unsigned short* bufB  = alloc(rows*256);
  unsigned short* bufC  = alloc(rows*512);
  unsigned short* preP  = alloc(rows*1024);
  unsigned short* preQ  = alloc(rows*1024);
  if (off * sizeof(unsigned short) > ws_size) return;

  float* out_mu = (float*)d_out;
  float* out_ls = out_mu + (size_t)LSEQ*BATCH*STATE;
  float* out_dn = out_ls + (size_t)LSEQ*BATCH*STATE;
  float* out_zn = out_dn + (size_t)BATCH*KDIM;

  WDescs wd;
  int wi = 0;
  auto add = [&](const float* s, unsigned short* d, int Kk, int Nn, int ld, int ro, int co){
    wd.d[wi].src = s; wd.d[wi].dst = d; wd.d[wi].K = Kk; wd.d[wi].N = Nn;
    wd.d[wi].ld = ld; wd.d[wi].rowoff = ro; wd.d[wi].coloff = co; wi++;
  };
  add(Wu,   Wu_t,  64, 256, 256, 0, 0);
  add(Wx,   Wx_t,  64, 256, 256, 0, 0);
  add(W_ih, Wih_t, 256, 256, 256, 0, 0);
  add(W_hh, Whh_t, 256, 256, 256, 0, 0);
  add(Wa1,  Wa1_t, 512, 256, 256, 0, 0);
  add(Wa2,  Wa2_t, 256, 256, 256, 0, 0);
  add(pf1W, fAp,            256, 512, 512, 128, 0);
  add(pf2W, fAp + 512*256,  256, 512, 512, 128, 0);
  add(qf1W, fAq,            256, 512, 512, 128, 0);
  add(qf2W, fAq + 512*256,  256, 512, 512, 128, 0);
  for (int c=0; c<4; c++){
    const float* s1 = (c < 2) ? pf1W : qf1W;
    const float* s2 = (c < 2) ? pf2W : qf2W;
    add(s1, Wzz + (size_t)(c*2+0)*32768, 128, 256, 512, 0, (c&1)*256);
    add(s2, Wzz + (size_t)(c*2+1)*32768, 128, 256, 512, 0, (c&1)*256);
  }
  add(pmuW, W2z + (size_t)(0*2+0)*32768, 256, 128, 128, 0,   0);
  add(plsW, W2z + (size_t)(0*2+1)*32768, 256, 128, 128, 0,   0);
  add(pmuW, W2z + (size_t)(1*2+0)*32768, 256, 128, 128, 256, 0);
  add(plsW, W2z + (size_t)(1*2+1)*32768, 256, 128, 128, 256, 0);
  add(qmuW, W2z + (size_t)(2*2+0)*32768, 256, 128, 128, 0,   0);
  add(qmuW, W2z + (size_t)(3*2+0)*32768, 256, 128, 128, 256, 0);

  convert_weights<<<dim3(512,24), 256, 0, stream>>>(wd);
  init_flags<<<8, 256, 0, stream>>>(flg);

  for (int c=0; c<NC; ++c){
    const int t0 = c * nsteps;
    const size_t row0 = (size_t)t0 * BATCH;

    GArgs e{};
    e.g[0] = GArg{ext + row0*64, Wu_t, bu, bu, bufA, 64, 256, 0,   64, 1, 1};
    e.g[1] = GArg{obs + row0*64, Wx_t, bx, bx, bufC, 64, 512, 256, 64, 1, 1};
    gemm_multi<<<dim3(gx,2,2), 256, 0, stream>>>(e);

    GArgs rn{};
    rn.g[0] = GArg{bufA, Wih_t, b_ih, b_ih, bufB, 256, 256, 0, 256, 0, 0};
    gemm_multi<<<dim3(gx,2,1), 256, 0, stream>>>(rn);

    rnn_chunk<<<16, 256, 0, stream>>>(bufB, Whh_t, b_hh, bufC, out_dn, d_state, t0, nsteps);

    GArgs a1{};
    a1.g[0] = GArg{bufC, Wa1_t, ba1, ba1, bufA, 512, 256, 0, 512, 1, 0};
    gemm_multi<<<dim3(gx,2,1), 256, 0, stream>>>(a1);

    GArgs a2{};
    a2.g[0] = GArg{bufA, Wa2_t, ba2, ba2, bufB, 256, 256, 0, 256, 0, 0};
    gemm_multi<<<dim3(gx,2,1), 256, 0, stream>>>(a2);

    GArgs pr{};
    pr.g[0] = GArg{bufB, fAp, pf1b, pf2b, preP, 256, 1024, 0, 256, 0, 0};
    pr.g[1] = GArg{bufC, fAq, qf1b, qf2b, preQ, 512, 1024, 0, 256, 0, 0};
    gemm_multi<<<dim3(gx,8,2), 256, 0, stream>>>(pr);

    zrec_mb<<<64, 512, 0, stream>>>(preP, preQ, Wzz, W2z,
                                    pmub, plsb, qmub, eps, out_mu, out_ls, out_zn,
                                    z_state, mbx, flg, t0, nsteps, c*nsteps);
  }
}